// Round 1
// 169.268 us; speedup vs baseline: 1.2110x; 1.2110x over previous
//
#include <hip/hip_runtime.h>

#define D 128
#define BSHIFT 6                 // 64 rows per coarse bucket
#define BCAP 1536                // entries per bucket; padded-to-8 mean ~1254, +7.6 sigma
#define EPB_A 2048               // edges per pass-A block: 391 blocks (was 98 -> 62% CUs idle)

typedef unsigned short ushort_t;
typedef unsigned int uint_t;

// ---- edge-index dtype probe (int64 vs int32), wave-uniform, ~free ----
__device__ __forceinline__ bool eidx_is64(const int* eidx) {
    int lane = threadIdx.x & 63;
    int probe = eidx[2 * lane + 1];              // L2-hit after first wave
    return __ballot(probe != 0) == 0ULL;         // int64 high halves all zero
}

__device__ __forceinline__ uint_t f2bf(float f) {
    union { float f; uint_t i; } v; v.f = f;
    return (v.i + 0x7fffu + ((v.i >> 16) & 1u)) >> 16;   // RNE
}
__device__ __forceinline__ float bf_lo(uint_t w) {
    union { uint_t i; float f; } v; v.i = w << 16; return v.f;
}
__device__ __forceinline__ float bf_hi(uint_t w) {
    union { uint_t i; float f; } v; v.i = w & 0xffff0000u; return v.f;
}

// ---- Pass A: coarse-bucket edges with LDS-aggregated reservation ----
__global__ __launch_bounds__(256) void bucketA_kernel(
    const int* __restrict__ eidx, int* __restrict__ gcur,
    int* __restrict__ bucket, int E, int NBUK) {
    __shared__ int lhist[1024];   // supports N <= 65536
    __shared__ int lbase[1024];
    bool is64 = eidx_is64(eidx);
    int t = threadIdx.x;
    for (int i = t; i < NBUK; i += 256) lhist[i] = 0;
    __syncthreads();

    int e0 = blockIdx.x * EPB_A;
    int e1 = min(e0 + EPB_A, E);
    for (int e = e0 + t; e < e1; e += 256) {
        int r = is64 ? eidx[2 * e] : eidx[e];
        atomicAdd(&lhist[r >> BSHIFT], 1);
    }
    __syncthreads();
    for (int i = t; i < NBUK; i += 256) {
        int h = lhist[i];
        lbase[i] = (h > 0) ? atomicAdd(&gcur[i], h) : 0;
        lhist[i] = 0;
    }
    __syncthreads();
    for (int e = e0 + t; e < e1; e += 256) {
        int r, c;
        if (is64) { r = eidx[2 * e]; c = eidx[2 * E + 2 * e]; }
        else      { r = eidx[e];     c = eidx[E + e]; }
        int b = r >> BSHIFT;
        int p = atomicAdd(&lhist[b], 1);   // LDS: cheap
        int idx = lbase[b] + p;
        if (idx < BCAP) bucket[b * BCAP + idx] = ((r & 63) << 24) | c;
    }
}

// ---- Merged Pass B + fp32->bf16 conv (independent work, one grid) ----
// blocks [0, NBUK): bucket -> packed per-row elist, segments PADDED TO 8
//   with dummy col = N (a zero row), so the fused gather has no scalar tail.
// blocks [NBUK, NBUK+cvb): x fp32 -> bf16 (halves gather set 25.6 -> 12.8 MB).
// block NBUK additionally zeroes the dummy row xb[N].
__global__ __launch_bounds__(256) void prep_kernel(
    const int* __restrict__ gcur, const int* __restrict__ bucket,
    int* __restrict__ elist, int* __restrict__ cnt,
    int* __restrict__ start, int N, int NBUK,
    const float* __restrict__ x, uint_t* __restrict__ xb, int total8) {
    __shared__ int lcnt[64], lpos[64], lstart[64];
    int t = threadIdx.x;

    if ((int)blockIdx.x >= NBUK) {               // ---- conv role ----
        int cb = blockIdx.x - NBUK;
        int i = cb * 256 + t;
        if (xb != nullptr && i < total8) {       // one thread = 8 elems
            const float4* p = (const float4*)(x + (size_t)i * 8);
            float4 a = p[0], b = p[1];
            uint4 o;
            o.x = f2bf(a.x) | (f2bf(a.y) << 16);
            o.y = f2bf(a.z) | (f2bf(a.w) << 16);
            o.z = f2bf(b.x) | (f2bf(b.y) << 16);
            o.w = f2bf(b.z) | (f2bf(b.w) << 16);
            *(uint4*)(xb + (size_t)i * 4) = o;
        }
        if (xb != nullptr && cb == 0 && t < 16) {
            // dummy zero row at index N (16 * uint4 = 256 B)
            uint4 z; z.x = 0u; z.y = 0u; z.z = 0u; z.w = 0u;
            ((uint4*)(xb + (size_t)N * (D / 2)))[t] = z;
        }
        return;
    }

    // ---- bucketB role ----
    int b = blockIdx.x;
    if (t < 64) { lcnt[t] = 0; lpos[t] = 0; }
    __syncthreads();
    int tot = min(gcur[b], BCAP);
    const int* bp = bucket + (size_t)b * BCAP;
    for (int i = t; i < tot; i += 256)
        atomicAdd(&lcnt[bp[i] >> 24], 1);
    __syncthreads();
    if (t == 0) {
        int run = 0;
        #pragma unroll
        for (int i = 0; i < 64; ++i) {
            lstart[i] = run;
            run += (lcnt[i] + 7) & ~7;     // 8-aligned, 8-padded segments
        }
    }
    __syncthreads();
    for (int i = t; i < tot; i += 256) {
        int v = bp[i];
        int rl = v >> 24;
        int p = atomicAdd(&lpos[rl], 1);
        int idx = lstart[rl] + p;
        if (idx < BCAP) elist[(size_t)b * BCAP + idx] = v & 0xFFFFFF;
    }
    // fill padding with the dummy row index (fp32 path reads only i < cnt,
    // so padding is invisible to it)
    if (t < 64) {
        int gr = (b << BSHIFT) + t;
        int c0 = lcnt[t];
        int pe = (c0 + 7) & ~7;
        for (int p = c0; p < pe; ++p) {
            int idx = lstart[t] + p;
            if (idx < BCAP) elist[(size_t)b * BCAP + idx] = N;
        }
        if (gr < N) { cnt[gr] = c0; start[gr] = b * BCAP + lstart[t]; }
    }
}

// ---- FUSED mean-aggregate (bf16 gather) + fp32 linear ----
// Quarter-wave per row: 16 lanes x uint4 (16 B) = full 256 B row, 4 rows and
// 1 KB per wave instruction (2x the old half-wave scheme). Segments are
// 8-padded so EVERY edge runs in the 8-deep pipeline; dummy reads hit the
// L1-resident zero row. elist int4s for chunk i+8 are prefetched before
// waiting on chunk i's gathers. sT writes use a (n + 4*(sl&7)) & 31 column
// rotation -> conflict-free (was 16-way, 3.8M conflict cycles).
#define GATHER8(CA, CB)                                                       \
    {                                                                         \
        uint4 g0 = *(const uint4*)(xs + (size_t)(CA).x * D);                  \
        uint4 g1 = *(const uint4*)(xs + (size_t)(CA).y * D);                  \
        uint4 g2 = *(const uint4*)(xs + (size_t)(CA).z * D);                  \
        uint4 g3 = *(const uint4*)(xs + (size_t)(CA).w * D);                  \
        uint4 g4 = *(const uint4*)(xs + (size_t)(CB).x * D);                  \
        uint4 g5 = *(const uint4*)(xs + (size_t)(CB).y * D);                  \
        uint4 g6 = *(const uint4*)(xs + (size_t)(CB).z * D);                  \
        uint4 g7 = *(const uint4*)(xs + (size_t)(CB).w * D);                  \
        a0 += ((bf_lo(g0.x) + bf_lo(g1.x)) + (bf_lo(g2.x) + bf_lo(g3.x)))     \
            + ((bf_lo(g4.x) + bf_lo(g5.x)) + (bf_lo(g6.x) + bf_lo(g7.x)));    \
        a1 += ((bf_hi(g0.x) + bf_hi(g1.x)) + (bf_hi(g2.x) + bf_hi(g3.x)))     \
            + ((bf_hi(g4.x) + bf_hi(g5.x)) + (bf_hi(g6.x) + bf_hi(g7.x)));    \
        a2 += ((bf_lo(g0.y) + bf_lo(g1.y)) + (bf_lo(g2.y) + bf_lo(g3.y)))     \
            + ((bf_lo(g4.y) + bf_lo(g5.y)) + (bf_lo(g6.y) + bf_lo(g7.y)));    \
        a3 += ((bf_hi(g0.y) + bf_hi(g1.y)) + (bf_hi(g2.y) + bf_hi(g3.y)))     \
            + ((bf_hi(g4.y) + bf_hi(g5.y)) + (bf_hi(g6.y) + bf_hi(g7.y)));    \
        a4 += ((bf_lo(g0.z) + bf_lo(g1.z)) + (bf_lo(g2.z) + bf_lo(g3.z)))     \
            + ((bf_lo(g4.z) + bf_lo(g5.z)) + (bf_lo(g6.z) + bf_lo(g7.z)));    \
        a5 += ((bf_hi(g0.z) + bf_hi(g1.z)) + (bf_hi(g2.z) + bf_hi(g3.z)))     \
            + ((bf_hi(g4.z) + bf_hi(g5.z)) + (bf_hi(g6.z) + bf_hi(g7.z)));    \
        a6 += ((bf_lo(g0.w) + bf_lo(g1.w)) + (bf_lo(g2.w) + bf_lo(g3.w)))     \
            + ((bf_lo(g4.w) + bf_lo(g5.w)) + (bf_lo(g6.w) + bf_lo(g7.w)));    \
        a7 += ((bf_hi(g0.w) + bf_hi(g1.w)) + (bf_hi(g2.w) + bf_hi(g3.w)))     \
            + ((bf_hi(g4.w) + bf_hi(g5.w)) + (bf_hi(g6.w) + bf_hi(g7.w)));    \
    }

__global__ __launch_bounds__(256, 6) void fused_bf_kernel(
    const ushort_t* __restrict__ xb, const int* __restrict__ elist,
    const int* __restrict__ cnt, const int* __restrict__ start,
    const float* __restrict__ W, const float* __restrict__ bias,
    float* __restrict__ out, int N) {
    __shared__ float sT[128 * 32];   // 16 KiB  [k][col], col = (n + 4*(sl&7)) & 31
    __shared__ float wc[16 * 132];   // 8.25 KiB [kk][j], one 16-wide K chunk
    int t = threadIdx.x;
    int lane = t & 63, wave = t >> 6;
    int qr = lane >> 4, sl = lane & 15;      // quarter, sublane
    int nbase = blockIdx.x * 32;
    int rot = (sl & 7) * 4;
    const ushort_t* xs = xb + 8 * sl;        // this lane's 16 B column slice

    // ---- Phase 1: gather means into sT ----
    #pragma unroll
    for (int quad = 0; quad < 2; ++quad) {
        int n = wave * 8 + quad * 4 + qr;    // this quarter's row
        int gn = nbase + n;
        int nr  = (gn < N) ? cnt[gn]   : 0;  // quarter-uniform
        int beg = (gn < N) ? start[gn] : 0;  // quarter-uniform, 8-aligned
        int nr8 = (nr + 7) & ~7;             // 8-padded trip count
        int mn = nr8;
        mn = min(mn, __shfl_xor(mn, 16));    // wave-min over 4 quarters
        mn = min(mn, __shfl_xor(mn, 32));
        float a0 = 0.f, a1 = 0.f, a2 = 0.f, a3 = 0.f;
        float a4 = 0.f, a5 = 0.f, a6 = 0.f, a7 = 0.f;
        const int* ep = elist + beg;
        int4 cA, cB;
        if (nr8 > 0) { cA = *(const int4*)ep; cB = *(const int4*)(ep + 4); }
        int i = 0;
        for (; i < mn; ) {                   // uniform 8-deep main loop
            int ni = i + 8;
            int4 nA2, nB2;
            if (ni < nr8) {                  // prefetch next chunk's elist
                nA2 = *(const int4*)(ep + ni);
                nB2 = *(const int4*)(ep + ni + 4);
            }
            GATHER8(cA, cB)
            cA = nA2; cB = nB2; i = ni;
        }
        for (; i < nr8; i += 8) {            // per-quarter 8-deep continuation
            int4 dA = *(const int4*)(ep + i);
            int4 dB = *(const int4*)(ep + i + 4);
            GATHER8(dA, dB)
        }
        float inv = (nr > 0) ? 1.0f / (float)nr : 0.0f;
        int col = (n + rot) & 31;
        int k0 = 8 * sl;
        sT[((k0 + 0) << 5) + col] = a0 * inv;
        sT[((k0 + 1) << 5) + col] = a1 * inv;
        sT[((k0 + 2) << 5) + col] = a2 * inv;
        sT[((k0 + 3) << 5) + col] = a3 * inv;
        sT[((k0 + 4) << 5) + col] = a4 * inv;
        sT[((k0 + 5) << 5) + col] = a5 * inv;
        sT[((k0 + 6) << 5) + col] = a6 * inv;
        sT[((k0 + 7) << 5) + col] = a7 * inv;
    }

    // ---- Phase 2: out[n][j] = sum_k sT[k][swz(n)] * W[j][k] + b[j] ----
    int jg = t & 31, ng = t >> 5;
    int j0 = jg * 4, n0 = ng * 4;
    float acc[4][4] = {};

    for (int kc = 0; kc < 8; ++kc) {
        __syncthreads();  // kc=0: sT complete; kc>0: prior wc reads done
        #pragma unroll
        for (int i = 0; i < 8; ++i) {
            int idx = t + i * 256;
            int j = idx >> 4, kk = idx & 15;
            wc[kk * 132 + j] = W[j * D + kc * 16 + kk];
        }
        __syncthreads();

        #pragma unroll
        for (int kk = 0; kk < 16; ++kk) {
            int k = kc * 16 + kk;
            int scol = (n0 + ((k >> 3) & 7) * 4) & 31;  // inverse of write swizzle
            float4 s4 = *(const float4*)(sT + (k << 5) + scol);
            float4 w4 = *(const float4*)(wc + kk * 132 + j0);
            acc[0][0] = fmaf(s4.x, w4.x, acc[0][0]); acc[0][1] = fmaf(s4.x, w4.y, acc[0][1]);
            acc[0][2] = fmaf(s4.x, w4.z, acc[0][2]); acc[0][3] = fmaf(s4.x, w4.w, acc[0][3]);
            acc[1][0] = fmaf(s4.y, w4.x, acc[1][0]); acc[1][1] = fmaf(s4.y, w4.y, acc[1][1]);
            acc[1][2] = fmaf(s4.y, w4.z, acc[1][2]); acc[1][3] = fmaf(s4.y, w4.w, acc[1][3]);
            acc[2][0] = fmaf(s4.z, w4.x, acc[2][0]); acc[2][1] = fmaf(s4.z, w4.y, acc[2][1]);
            acc[2][2] = fmaf(s4.z, w4.z, acc[2][2]); acc[2][3] = fmaf(s4.z, w4.w, acc[2][3]);
            acc[3][0] = fmaf(s4.w, w4.x, acc[3][0]); acc[3][1] = fmaf(s4.w, w4.y, acc[3][1]);
            acc[3][2] = fmaf(s4.w, w4.z, acc[3][2]); acc[3][3] = fmaf(s4.w, w4.w, acc[3][3]);
        }
    }

    float4 b4 = *(const float4*)(bias + j0);
    #pragma unroll
    for (int i = 0; i < 4; ++i) {
        int gn = nbase + n0 + i;
        if (gn >= N) continue;
        float4 o;
        o.x = acc[i][0] + b4.x;
        o.y = acc[i][1] + b4.y;
        o.z = acc[i][2] + b4.z;
        o.w = acc[i][3] + b4.w;
        *(float4*)(out + (size_t)gn * D + j0) = o;
    }
}

// ---- fp32 fused variant (R10-proven; used when ws can't hold xb).
// Reads only i < cnt entries, so elist padding is invisible to it. ----
__global__ __launch_bounds__(256, 6) void fused_kernel(
    const float* __restrict__ x, const int* __restrict__ elist,
    const int* __restrict__ cnt, const int* __restrict__ start,
    const float* __restrict__ W, const float* __restrict__ bias,
    float* __restrict__ out, int N) {
    __shared__ float sT[128 * 36];
    __shared__ float wc[16 * 132];
    int t = threadIdx.x;
    int lane = t & 63, wave = t >> 6;
    int half = lane >> 5, sl = lane & 31;
    int nbase = blockIdx.x * 32;

    #pragma unroll
    for (int pair = 0; pair < 4; ++pair) {
        int n = wave * 8 + pair * 2 + half;
        int gn = nbase + n;
        int nr  = (gn < N) ? cnt[gn]   : 0;
        int beg = (gn < N) ? start[gn] : 0;
        int nro  = __shfl(nr, lane ^ 32);
        int both = min(nr, nro);
        float ax = 0.f, ay = 0.f, az = 0.f, aw = 0.f;
        int i = 0;
        for (; i + 8 <= both; i += 8) {
            int4 cA = *(const int4*)(elist + beg + i);
            int4 cB = *(const int4*)(elist + beg + i + 4);
            float4 v0 = *(const float4*)(x + (size_t)cA.x * D + 4 * sl);
            float4 v1 = *(const float4*)(x + (size_t)cA.y * D + 4 * sl);
            float4 v2 = *(const float4*)(x + (size_t)cA.z * D + 4 * sl);
            float4 v3 = *(const float4*)(x + (size_t)cA.w * D + 4 * sl);
            float4 v4 = *(const float4*)(x + (size_t)cB.x * D + 4 * sl);
            float4 v5 = *(const float4*)(x + (size_t)cB.y * D + 4 * sl);
            float4 v6 = *(const float4*)(x + (size_t)cB.z * D + 4 * sl);
            float4 v7 = *(const float4*)(x + (size_t)cB.w * D + 4 * sl);
            ax += ((v0.x + v1.x) + (v2.x + v3.x)) + ((v4.x + v5.x) + (v6.x + v7.x));
            ay += ((v0.y + v1.y) + (v2.y + v3.y)) + ((v4.y + v5.y) + (v6.y + v7.y));
            az += ((v0.z + v1.z) + (v2.z + v3.z)) + ((v4.z + v5.z) + (v6.z + v7.z));
            aw += ((v0.w + v1.w) + (v2.w + v3.w)) + ((v4.w + v5.w) + (v6.w + v7.w));
        }
        for (; i < nr; ++i) {
            int c0 = elist[beg + i];
            float4 v = *(const float4*)(x + (size_t)c0 * D + 4 * sl);
            ax += v.x; ay += v.y; az += v.z; aw += v.w;
        }
        float inv = (nr > 0) ? 1.0f / (float)nr : 0.0f;
        int k0 = 4 * sl;
        sT[(k0 + 0) * 36 + n] = ax * inv;
        sT[(k0 + 1) * 36 + n] = ay * inv;
        sT[(k0 + 2) * 36 + n] = az * inv;
        sT[(k0 + 3) * 36 + n] = aw * inv;
    }

    int jg = t & 31, ng = t >> 5;
    int j0 = jg * 4, n0 = ng * 4;
    float acc[4][4] = {};
    for (int kc = 0; kc < 8; ++kc) {
        __syncthreads();
        #pragma unroll
        for (int i = 0; i < 8; ++i) {
            int idx = t + i * 256;
            int j = idx >> 4, kk = idx & 15;
            wc[kk * 132 + j] = W[j * D + kc * 16 + kk];
        }
        __syncthreads();
        #pragma unroll
        for (int kk = 0; kk < 16; ++kk) {
            int k = kc * 16 + kk;
            float4 s4 = *(const float4*)(sT + k * 36 + n0);
            float4 w4 = *(const float4*)(wc + kk * 132 + j0);
            acc[0][0] = fmaf(s4.x, w4.x, acc[0][0]); acc[0][1] = fmaf(s4.x, w4.y, acc[0][1]);
            acc[0][2] = fmaf(s4.x, w4.z, acc[0][2]); acc[0][3] = fmaf(s4.x, w4.w, acc[0][3]);
            acc[1][0] = fmaf(s4.y, w4.x, acc[1][0]); acc[1][1] = fmaf(s4.y, w4.y, acc[1][1]);
            acc[1][2] = fmaf(s4.y, w4.z, acc[1][2]); acc[1][3] = fmaf(s4.y, w4.w, acc[1][3]);
            acc[2][0] = fmaf(s4.z, w4.x, acc[2][0]); acc[2][1] = fmaf(s4.z, w4.y, acc[2][1]);
            acc[2][2] = fmaf(s4.z, w4.z, acc[2][2]); acc[2][3] = fmaf(s4.z, w4.w, acc[2][3]);
            acc[3][0] = fmaf(s4.w, w4.x, acc[3][0]); acc[3][1] = fmaf(s4.w, w4.y, acc[3][1]);
            acc[3][2] = fmaf(s4.w, w4.z, acc[3][2]); acc[3][3] = fmaf(s4.w, w4.w, acc[3][3]);
        }
    }
    float4 b4 = *(const float4*)(bias + j0);
    #pragma unroll
    for (int i = 0; i < 4; ++i) {
        int gn = nbase + n0 + i;
        if (gn >= N) continue;
        float4 o;
        o.x = acc[i][0] + b4.x;
        o.y = acc[i][1] + b4.y;
        o.z = acc[i][2] + b4.z;
        o.w = acc[i][3] + b4.w;
        *(float4*)(out + (size_t)gn * D + j0) = o;
    }
}

// ==== last-resort fallback: atomic scatter + divide + gemm (proven) ====
__global__ __launch_bounds__(256) void scatter_kernel(
    const float* __restrict__ x, const int* __restrict__ eidx,
    float* summed, float* __restrict__ counts, int E) {
    int t = blockIdx.x * 256 + threadIdx.x;
    int lane = threadIdx.x & 63;
    bool is64 = eidx_is64(eidx);
    int e = t >> 6;
    if (e >= E) return;
    int d = lane * 2;
    int r, c;
    if (is64) { r = eidx[2 * e]; c = eidx[2 * E + 2 * e]; }
    else      { r = eidx[e];     c = eidx[E + e]; }
    float2 v = *(const float2*)(x + (size_t)c * D + d);
    float* dst = summed + (size_t)r * D + d;
    atomicAdd(dst, v.x);
    atomicAdd(dst + 1, v.y);
    if (lane == 0) atomicAdd(counts + r, 1.0f);
}

__global__ __launch_bounds__(256) void divide_kernel(
    float* __restrict__ sums, const float* __restrict__ counts, int N) {
    int g = blockIdx.x * 256 + threadIdx.x;
    int r = g >> 6, lane = g & 63;
    if (r >= N) return;
    float inv = 1.0f / fmaxf(counts[r], 1.0f);
    float2* p = (float2*)(sums + (size_t)r * D + 2 * lane);
    float2 v = *p;
    v.x *= inv; v.y *= inv;
    *p = v;
}

__global__ __launch_bounds__(256) void gemm_kernel(
    float* inout, const float* __restrict__ W,
    const float* __restrict__ bias, int N) {
    __shared__ float sT[128 * 36];
    __shared__ float wc[32 * 132];
    int t = threadIdx.x;
    int nbase = blockIdx.x * 32;
    #pragma unroll
    for (int i = 0; i < 16; ++i) {
        int idx = t + i * 256;
        int n = idx >> 7, k = idx & 127;
        int gn = nbase + n;
        sT[k * 36 + n] = (gn < N) ? inout[(size_t)gn * D + k] : 0.0f;
    }
    int jg = t & 31, ng = t >> 5;
    int j0 = jg * 4, n0 = ng * 4;
    float acc[4][4] = {};
    for (int kc = 0; kc < 4; ++kc) {
        __syncthreads();
        #pragma unroll
        for (int i = 0; i < 16; ++i) {
            int idx = t + i * 256;
            int j = idx >> 5, kk = idx & 31;
            wc[kk * 132 + j] = W[j * D + kc * 32 + kk];
        }
        __syncthreads();
        #pragma unroll 8
        for (int kk = 0; kk < 32; ++kk) {
            int k = kc * 32 + kk;
            float4 s4 = *(const float4*)(sT + k * 36 + n0);
            float4 w4 = *(const float4*)(wc + kk * 132 + j0);
            acc[0][0] = fmaf(s4.x, w4.x, acc[0][0]); acc[0][1] = fmaf(s4.x, w4.y, acc[0][1]);
            acc[0][2] = fmaf(s4.x, w4.z, acc[0][2]); acc[0][3] = fmaf(s4.x, w4.w, acc[0][3]);
            acc[1][0] = fmaf(s4.y, w4.x, acc[1][0]); acc[1][1] = fmaf(s4.y, w4.y, acc[1][1]);
            acc[1][2] = fmaf(s4.y, w4.z, acc[1][2]); acc[1][3] = fmaf(s4.y, w4.w, acc[1][3]);
            acc[2][0] = fmaf(s4.z, w4.x, acc[2][0]); acc[2][1] = fmaf(s4.z, w4.y, acc[2][1]);
            acc[2][2] = fmaf(s4.z, w4.z, acc[2][2]); acc[2][3] = fmaf(s4.z, w4.w, acc[2][3]);
            acc[3][0] = fmaf(s4.w, w4.x, acc[3][0]); acc[3][1] = fmaf(s4.w, w4.y, acc[3][1]);
            acc[3][2] = fmaf(s4.w, w4.z, acc[3][2]); acc[3][3] = fmaf(s4.w, w4.w, acc[3][3]);
        }
    }
    float4 b4 = *(const float4*)(bias + j0);
    #pragma unroll
    for (int i = 0; i < 4; ++i) {
        int gn = nbase + n0 + i;
        if (gn >= N) continue;
        float4 o;
        o.x = acc[i][0] + b4.x;
        o.y = acc[i][1] + b4.y;
        o.z = acc[i][2] + b4.z;
        o.w = acc[i][3] + b4.w;
        *(float4*)(inout + (size_t)gn * D + j0) = o;
    }
}

extern "C" void kernel_launch(void* const* d_in, const int* in_sizes, int n_in,
                              void* d_out, int out_size, void* d_ws, size_t ws_size,
                              hipStream_t stream) {
    // setup_inputs order: x, edge_index, batch_size, num_nodes, W, b
    const float* x = (const float*)d_in[0];
    const int* eidx = (const int*)d_in[1];
    const float* W = (const float*)d_in[4];
    const float* b = (const float*)d_in[5];
    float* out = (float*)d_out;

    int N = in_sizes[0] / D;   // 50000
    int E = in_sizes[1] / 2;   // 800000
    int NBUK = (N + 63) >> BSHIFT;   // 782
    int fb = (N + 31) / 32;
    int ab = (E + EPB_A - 1) / EPB_A;

    // ws layout, 256B-aligned segments.
    size_t o0 = 0;
    size_t o_gc = o0;  o0 += ((size_t)NBUK * 4 + 255) & ~255ULL;
    size_t o_cn = o0;  o0 += ((size_t)N * 4 + 255) & ~255ULL;
    size_t o_st = o0;  o0 += ((size_t)N * 4 + 255) & ~255ULL;
    size_t o_bk = o0;  o0 += (size_t)NBUK * BCAP * 4;
    size_t o_el = o0;  o0 += (size_t)NBUK * BCAP * 4;
    size_t base_need = o0;
    size_t o_xb = o0;  size_t bf_need = o0 + (size_t)(N + 1) * D * 2;  // bf16 x + dummy row

    bool cap_ok = (N <= 65536) && ((size_t)NBUK * BCAP >= (size_t)E);

    int cvb = (N * D / 8 + 255) / 256;

    if (cap_ok && ws_size >= bf_need) {
        char* ws = (char*)d_ws;
        int*      gcur  = (int*)(ws + o_gc);
        int*      cnt   = (int*)(ws + o_cn);
        int*      start = (int*)(ws + o_st);
        int*      bkt   = (int*)(ws + o_bk);
        int*      elist = (int*)(ws + o_el);
        ushort_t* xb    = (ushort_t*)(ws + o_xb);

        hipMemsetAsync(gcur, 0, (size_t)NBUK * 4, stream);  // 3 KB only
        bucketA_kernel<<<ab, 256, 0, stream>>>(eidx, gcur, bkt, E, NBUK);
        prep_kernel<<<NBUK + cvb, 256, 0, stream>>>(
            gcur, bkt, elist, cnt, start, N, NBUK, x, (uint_t*)xb, N * D / 8);
        fused_bf_kernel<<<fb, 256, 0, stream>>>(xb, elist, cnt, start, W, b, out, N);
    } else if (cap_ok && ws_size >= base_need) {
        char* ws = (char*)d_ws;
        int* gcur  = (int*)(ws + o_gc);
        int* cnt   = (int*)(ws + o_cn);
        int* start = (int*)(ws + o_st);
        int* bkt   = (int*)(ws + o_bk);
        int* elist = (int*)(ws + o_el);

        hipMemsetAsync(gcur, 0, (size_t)NBUK * 4, stream);
        bucketA_kernel<<<ab, 256, 0, stream>>>(eidx, gcur, bkt, E, NBUK);
        prep_kernel<<<NBUK, 256, 0, stream>>>(
            gcur, bkt, elist, cnt, start, N, NBUK, nullptr, nullptr, 0);
        fused_kernel<<<fb, 256, 0, stream>>>(x, elist, cnt, start, W, b, out, N);
    } else {
        float* counts = (float*)d_ws;
        hipMemsetAsync(d_out, 0, (size_t)N * D * sizeof(float), stream);
        hipMemsetAsync(d_ws, 0, (size_t)N * sizeof(float), stream);
        int sb = (E * 64 + 255) / 256;
        scatter_kernel<<<sb, 256, 0, stream>>>(x, eidx, out, counts, E);
        int db = (N * 64 + 255) / 256;
        divide_kernel<<<db, 256, 0, stream>>>(out, counts, N);
        gemm_kernel<<<fb, 256, 0, stream>>>(out, W, b, N);
    }
}

// Round 2
// 164.497 us; speedup vs baseline: 1.2461x; 1.0290x over previous
//
#include <hip/hip_runtime.h>

#define D 128
#define BSHIFT 6                 // 64 rows per coarse bucket
#define BCAP 1536                // entries per bucket; padded-to-8 mean ~1254, +7.6 sigma
#define EPB_A 2048               // edges per pass-A block: 391 blocks

typedef unsigned short ushort_t;
typedef unsigned int uint_t;
typedef __attribute__((ext_vector_type(8))) short short8_t;   // 8 bf16 = 4 VGPR
typedef __attribute__((ext_vector_type(4))) float f32x4_t;    // mfma C/D

// ---- edge-index dtype probe (int64 vs int32), wave-uniform, ~free ----
__device__ __forceinline__ bool eidx_is64(const int* eidx) {
    int lane = threadIdx.x & 63;
    int probe = eidx[2 * lane + 1];              // L2-hit after first wave
    return __ballot(probe != 0) == 0ULL;         // int64 high halves all zero
}

__device__ __forceinline__ uint_t f2bf(float f) {
    union { float f; uint_t i; } v; v.f = f;
    return (v.i + 0x7fffu + ((v.i >> 16) & 1u)) >> 16;   // RNE
}
__device__ __forceinline__ float bf_lo(uint_t w) {
    union { uint_t i; float f; } v; v.i = w << 16; return v.f;
}
__device__ __forceinline__ float bf_hi(uint_t w) {
    union { uint_t i; float f; } v; v.i = w & 0xffff0000u; return v.f;
}

// ---- Pass A: coarse-bucket edges with LDS-aggregated reservation ----
__global__ __launch_bounds__(256) void bucketA_kernel(
    const int* __restrict__ eidx, int* __restrict__ gcur,
    int* __restrict__ bucket, int E, int NBUK) {
    __shared__ int lhist[1024];   // supports N <= 65536
    __shared__ int lbase[1024];
    bool is64 = eidx_is64(eidx);
    int t = threadIdx.x;
    for (int i = t; i < NBUK; i += 256) lhist[i] = 0;
    __syncthreads();

    int e0 = blockIdx.x * EPB_A;
    int e1 = min(e0 + EPB_A, E);
    for (int e = e0 + t; e < e1; e += 256) {
        int r = is64 ? eidx[2 * e] : eidx[e];
        atomicAdd(&lhist[r >> BSHIFT], 1);
    }
    __syncthreads();
    for (int i = t; i < NBUK; i += 256) {
        int h = lhist[i];
        lbase[i] = (h > 0) ? atomicAdd(&gcur[i], h) : 0;
        lhist[i] = 0;
    }
    __syncthreads();
    for (int e = e0 + t; e < e1; e += 256) {
        int r, c;
        if (is64) { r = eidx[2 * e]; c = eidx[2 * E + 2 * e]; }
        else      { r = eidx[e];     c = eidx[E + e]; }
        int b = r >> BSHIFT;
        int p = atomicAdd(&lhist[b], 1);   // LDS: cheap
        int idx = lbase[b] + p;
        if (idx < BCAP) bucket[b * BCAP + idx] = ((r & 63) << 24) | c;
    }
}

// ---- Merged Pass B + fp32->bf16 conv of x AND W (independent work) ----
// blocks [0, NBUK): bucket -> packed per-row elist, segments PADDED TO 8
// blocks [NBUK, NBUK+cvb): x fp32 -> bf16 (block NBUK also zeroes dummy row)
// blocks [NBUK+cvb, NBUK+cvb+8): W fp32 -> bf16 (32 KB, for MFMA B-frags)
__global__ __launch_bounds__(256) void prep_kernel(
    const int* __restrict__ gcur, const int* __restrict__ bucket,
    int* __restrict__ elist, int* __restrict__ cnt,
    int* __restrict__ start, int N, int NBUK,
    const float* __restrict__ x, uint_t* __restrict__ xb, int total8, int cvb,
    const float* __restrict__ Wsrc, uint_t* __restrict__ wb) {
    __shared__ int lcnt[64], lpos[64], lstart[64];
    int t = threadIdx.x;

    if ((int)blockIdx.x >= NBUK) {               // ---- conv roles ----
        if (xb == nullptr) return;
        int cb = blockIdx.x - NBUK;
        if (cb < cvb) {                          // x conversion
            int i = cb * 256 + t;
            if (i < total8) {                    // one thread = 8 elems
                const float4* p = (const float4*)(x + (size_t)i * 8);
                float4 a = p[0], b = p[1];
                uint4 o;
                o.x = f2bf(a.x) | (f2bf(a.y) << 16);
                o.y = f2bf(a.z) | (f2bf(a.w) << 16);
                o.z = f2bf(b.x) | (f2bf(b.y) << 16);
                o.w = f2bf(b.z) | (f2bf(b.w) << 16);
                *(uint4*)(xb + (size_t)i * 4) = o;
            }
            if (cb == 0 && t < 16) {
                // dummy zero row at index N (16 * uint4 = 256 B)
                uint4 z; z.x = 0u; z.y = 0u; z.z = 0u; z.w = 0u;
                ((uint4*)(xb + (size_t)N * (D / 2)))[t] = z;
            }
        } else {                                 // W conversion (D*D/8 = 2048 items)
            int i = (cb - cvb) * 256 + t;
            if (i < D * D / 8) {
                const float4* p = (const float4*)(Wsrc + (size_t)i * 8);
                float4 a = p[0], b = p[1];
                uint4 o;
                o.x = f2bf(a.x) | (f2bf(a.y) << 16);
                o.y = f2bf(a.z) | (f2bf(a.w) << 16);
                o.z = f2bf(b.x) | (f2bf(b.y) << 16);
                o.w = f2bf(b.z) | (f2bf(b.w) << 16);
                *(uint4*)(wb + (size_t)i * 4) = o;
            }
        }
        return;
    }

    // ---- bucketB role ----
    int b = blockIdx.x;
    if (t < 64) { lcnt[t] = 0; lpos[t] = 0; }
    __syncthreads();
    int tot = min(gcur[b], BCAP);
    const int* bp = bucket + (size_t)b * BCAP;
    for (int i = t; i < tot; i += 256)
        atomicAdd(&lcnt[bp[i] >> 24], 1);
    __syncthreads();
    if (t == 0) {
        int run = 0;
        #pragma unroll
        for (int i = 0; i < 64; ++i) {
            lstart[i] = run;
            run += (lcnt[i] + 7) & ~7;     // 8-aligned, 8-padded segments
        }
    }
    __syncthreads();
    for (int i = t; i < tot; i += 256) {
        int v = bp[i];
        int rl = v >> 24;
        int p = atomicAdd(&lpos[rl], 1);
        int idx = lstart[rl] + p;
        if (idx < BCAP) elist[(size_t)b * BCAP + idx] = v & 0xFFFFFF;
    }
    // fill padding with the dummy row index (fp32 path reads only i < cnt)
    if (t < 64) {
        int gr = (b << BSHIFT) + t;
        int c0 = lcnt[t];
        int pe = (c0 + 7) & ~7;
        for (int p = c0; p < pe; ++p) {
            int idx = lstart[t] + p;
            if (idx < BCAP) elist[(size_t)b * BCAP + idx] = N;
        }
        if (gr < N) { cnt[gr] = c0; start[gr] = b * BCAP + lstart[t]; }
    }
}

// ---- FUSED mean-aggregate (bf16 gather) + MFMA linear ----
// Phase 1: quarter-wave per row, uint4 (16 B/lane) gathers, 8-padded segments
//   (no scalar tail; dummies hit the L1-resident zero row). Means are packed
//   to bf16 and stored to an 8.5 KiB LDS A-tile [32][128+8pad].
// Phase 2: the [32x128]x[128x128] GEMM on the MATRIX pipe:
//   v_mfma_f32_16x16x32_bf16, A-frags from LDS (pad -> 2-way banks = free),
//   B-frags read straight from global bf16 W (64 KB, L2-resident).
//   Replaces 1.6 GB of LDS traffic + 2048 VALU FMAs/thread (~23 us floor)
//   with 64 mfma/block (~1 us) + ~3 us of L2 W reads.
#define GATHER8(CA, CB)                                                       \
    {                                                                         \
        uint4 g0 = *(const uint4*)(xs + (size_t)(CA).x * D);                  \
        uint4 g1 = *(const uint4*)(xs + (size_t)(CA).y * D);                  \
        uint4 g2 = *(const uint4*)(xs + (size_t)(CA).z * D);                  \
        uint4 g3 = *(const uint4*)(xs + (size_t)(CA).w * D);                  \
        uint4 g4 = *(const uint4*)(xs + (size_t)(CB).x * D);                  \
        uint4 g5 = *(const uint4*)(xs + (size_t)(CB).y * D);                  \
        uint4 g6 = *(const uint4*)(xs + (size_t)(CB).z * D);                  \
        uint4 g7 = *(const uint4*)(xs + (size_t)(CB).w * D);                  \
        a0 += ((bf_lo(g0.x) + bf_lo(g1.x)) + (bf_lo(g2.x) + bf_lo(g3.x)))     \
            + ((bf_lo(g4.x) + bf_lo(g5.x)) + (bf_lo(g6.x) + bf_lo(g7.x)));    \
        a1 += ((bf_hi(g0.x) + bf_hi(g1.x)) + (bf_hi(g2.x) + bf_hi(g3.x)))     \
            + ((bf_hi(g4.x) + bf_hi(g5.x)) + (bf_hi(g6.x) + bf_hi(g7.x)));    \
        a2 += ((bf_lo(g0.y) + bf_lo(g1.y)) + (bf_lo(g2.y) + bf_lo(g3.y)))     \
            + ((bf_lo(g4.y) + bf_lo(g5.y)) + (bf_lo(g6.y) + bf_lo(g7.y)));    \
        a3 += ((bf_hi(g0.y) + bf_hi(g1.y)) + (bf_hi(g2.y) + bf_hi(g3.y)))     \
            + ((bf_hi(g4.y) + bf_hi(g5.y)) + (bf_hi(g6.y) + bf_hi(g7.y)));    \
        a4 += ((bf_lo(g0.z) + bf_lo(g1.z)) + (bf_lo(g2.z) + bf_lo(g3.z)))     \
            + ((bf_lo(g4.z) + bf_lo(g5.z)) + (bf_lo(g6.z) + bf_lo(g7.z)));    \
        a5 += ((bf_hi(g0.z) + bf_hi(g1.z)) + (bf_hi(g2.z) + bf_hi(g3.z)))     \
            + ((bf_hi(g4.z) + bf_hi(g5.z)) + (bf_hi(g6.z) + bf_hi(g7.z)));    \
        a6 += ((bf_lo(g0.w) + bf_lo(g1.w)) + (bf_lo(g2.w) + bf_lo(g3.w)))     \
            + ((bf_lo(g4.w) + bf_lo(g5.w)) + (bf_lo(g6.w) + bf_lo(g7.w)));    \
        a7 += ((bf_hi(g0.w) + bf_hi(g1.w)) + (bf_hi(g2.w) + bf_hi(g3.w)))     \
            + ((bf_hi(g4.w) + bf_hi(g5.w)) + (bf_hi(g6.w) + bf_hi(g7.w)));    \
    }

__global__ __launch_bounds__(256, 6) void fused_bf_kernel(
    const ushort_t* __restrict__ xb, const int* __restrict__ elist,
    const int* __restrict__ cnt, const int* __restrict__ start,
    const ushort_t* __restrict__ Wb, const float* __restrict__ bias,
    float* __restrict__ out, int N) {
    __shared__ ushort_t sA[32 * 136];   // 8.5 KiB  [n][k] bf16, +8-short row pad
    int t = threadIdx.x;
    int lane = t & 63, wave = t >> 6;
    int qr = lane >> 4, sl = lane & 15;      // quarter, sublane
    int nbase = blockIdx.x * 32;
    const ushort_t* xs = xb + 8 * sl;        // this lane's 16 B column slice

    // ---- Phase 1: gather means -> bf16 LDS A-tile ----
    #pragma unroll
    for (int quad = 0; quad < 2; ++quad) {
        int n = wave * 8 + quad * 4 + qr;    // this quarter's row
        int gn = nbase + n;
        int nr  = (gn < N) ? cnt[gn]   : 0;  // quarter-uniform
        int beg = (gn < N) ? start[gn] : 0;  // quarter-uniform, 8-aligned
        int nr8 = (nr + 7) & ~7;             // 8-padded trip count
        int mn = nr8;
        mn = min(mn, __shfl_xor(mn, 16));    // wave-min over 4 quarters
        mn = min(mn, __shfl_xor(mn, 32));
        float a0 = 0.f, a1 = 0.f, a2 = 0.f, a3 = 0.f;
        float a4 = 0.f, a5 = 0.f, a6 = 0.f, a7 = 0.f;
        const int* ep = elist + beg;
        int4 cA, cB;
        if (nr8 > 0) { cA = *(const int4*)ep; cB = *(const int4*)(ep + 4); }
        int i = 0;
        for (; i < mn; ) {                   // uniform 8-deep main loop
            int ni = i + 8;
            int4 nA2, nB2;
            if (ni < nr8) {                  // prefetch next chunk's elist
                nA2 = *(const int4*)(ep + ni);
                nB2 = *(const int4*)(ep + ni + 4);
            }
            GATHER8(cA, cB)
            cA = nA2; cB = nB2; i = ni;
        }
        for (; i < nr8; i += 8) {            // per-quarter 8-deep continuation
            int4 dA = *(const int4*)(ep + i);
            int4 dB = *(const int4*)(ep + i + 4);
            GATHER8(dA, dB)
        }
        float inv = (nr > 0) ? 1.0f / (float)nr : 0.0f;
        uint4 pk;
        pk.x = f2bf(a0 * inv) | (f2bf(a1 * inv) << 16);
        pk.y = f2bf(a2 * inv) | (f2bf(a3 * inv) << 16);
        pk.z = f2bf(a4 * inv) | (f2bf(a5 * inv) << 16);
        pk.w = f2bf(a6 * inv) | (f2bf(a7 * inv) << 16);
        *(uint4*)(sA + n * 136 + 8 * sl) = pk;
    }
    __syncthreads();

    // ---- Phase 2: out[n][j] = mean[n][:] . W[j][:] + b[j]  via MFMA ----
    // wave -> (row-tile rt = wave&1, col-group jgrp = wave>>1 of 4 j-tiles)
    // A-frag: lane holds A[l&15][(l>>4)*8 + e];  B = W^T so lane holds
    // W[j = jt*16 + (l&15)][k .. k+7] -- contiguous global bf16 read.
    {
        int rt = wave & 1, jgrp = wave >> 1;
        int ml = lane & 15, kh = lane >> 4;
        short8_t afr[4];
        #pragma unroll
        for (int ks = 0; ks < 4; ++ks)
            afr[ks] = *(const short8_t*)(sA + (rt * 16 + ml) * 136 + ks * 32 + kh * 8);
        f32x4_t acc[4];
        #pragma unroll
        for (int q = 0; q < 4; ++q) acc[q] = (f32x4_t){0.f, 0.f, 0.f, 0.f};
        #pragma unroll
        for (int q = 0; q < 4; ++q) {
            int j = (jgrp * 4 + q) * 16 + ml;
            #pragma unroll
            for (int ks = 0; ks < 4; ++ks) {
                short8_t bfr = *(const short8_t*)(Wb + (size_t)j * D + ks * 32 + kh * 8);
                acc[q] = __builtin_amdgcn_mfma_f32_16x16x32_bf16(afr[ks], bfr, acc[q], 0, 0, 0);
            }
        }
        // C/D layout: col = lane&15 (j), row = (lane>>4)*4 + reg (n)
        #pragma unroll
        for (int q = 0; q < 4; ++q) {
            int j = (jgrp * 4 + q) * 16 + ml;
            float bj = bias[j];
            #pragma unroll
            for (int r = 0; r < 4; ++r) {
                int gn = nbase + rt * 16 + kh * 4 + r;
                if (gn < N) out[(size_t)gn * D + j] = acc[q][r] + bj;
            }
        }
    }
}

// ---- fp32 fused variant (R10-proven; used when ws can't hold xb).
// Reads only i < cnt entries, so elist padding is invisible to it. ----
__global__ __launch_bounds__(256, 6) void fused_kernel(
    const float* __restrict__ x, const int* __restrict__ elist,
    const int* __restrict__ cnt, const int* __restrict__ start,
    const float* __restrict__ W, const float* __restrict__ bias,
    float* __restrict__ out, int N) {
    __shared__ float sT[128 * 36];
    __shared__ float wc[16 * 132];
    int t = threadIdx.x;
    int lane = t & 63, wave = t >> 6;
    int half = lane >> 5, sl = lane & 31;
    int nbase = blockIdx.x * 32;

    #pragma unroll
    for (int pair = 0; pair < 4; ++pair) {
        int n = wave * 8 + pair * 2 + half;
        int gn = nbase + n;
        int nr  = (gn < N) ? cnt[gn]   : 0;
        int beg = (gn < N) ? start[gn] : 0;
        int nro  = __shfl(nr, lane ^ 32);
        int both = min(nr, nro);
        float ax = 0.f, ay = 0.f, az = 0.f, aw = 0.f;
        int i = 0;
        for (; i + 8 <= both; i += 8) {
            int4 cA = *(const int4*)(elist + beg + i);
            int4 cB = *(const int4*)(elist + beg + i + 4);
            float4 v0 = *(const float4*)(x + (size_t)cA.x * D + 4 * sl);
            float4 v1 = *(const float4*)(x + (size_t)cA.y * D + 4 * sl);
            float4 v2 = *(const float4*)(x + (size_t)cA.z * D + 4 * sl);
            float4 v3 = *(const float4*)(x + (size_t)cA.w * D + 4 * sl);
            float4 v4 = *(const float4*)(x + (size_t)cB.x * D + 4 * sl);
            float4 v5 = *(const float4*)(x + (size_t)cB.y * D + 4 * sl);
            float4 v6 = *(const float4*)(x + (size_t)cB.z * D + 4 * sl);
            float4 v7 = *(const float4*)(x + (size_t)cB.w * D + 4 * sl);
            ax += ((v0.x + v1.x) + (v2.x + v3.x)) + ((v4.x + v5.x) + (v6.x + v7.x));
            ay += ((v0.y + v1.y) + (v2.y + v3.y)) + ((v4.y + v5.y) + (v6.y + v7.y));
            az += ((v0.z + v1.z) + (v2.z + v3.z)) + ((v4.z + v5.z) + (v6.z + v7.z));
            aw += ((v0.w + v1.w) + (v2.w + v3.w)) + ((v4.w + v5.w) + (v6.w + v7.w));
        }
        for (; i < nr; ++i) {
            int c0 = elist[beg + i];
            float4 v = *(const float4*)(x + (size_t)c0 * D + 4 * sl);
            ax += v.x; ay += v.y; az += v.z; aw += v.w;
        }
        float inv = (nr > 0) ? 1.0f / (float)nr : 0.0f;
        int k0 = 4 * sl;
        sT[(k0 + 0) * 36 + n] = ax * inv;
        sT[(k0 + 1) * 36 + n] = ay * inv;
        sT[(k0 + 2) * 36 + n] = az * inv;
        sT[(k0 + 3) * 36 + n] = aw * inv;
    }

    int jg = t & 31, ng = t >> 5;
    int j0 = jg * 4, n0 = ng * 4;
    float acc[4][4] = {};
    for (int kc = 0; kc < 8; ++kc) {
        __syncthreads();
        #pragma unroll
        for (int i = 0; i < 8; ++i) {
            int idx = t + i * 256;
            int j = idx >> 4, kk = idx & 15;
            wc[kk * 132 + j] = W[j * D + kc * 16 + kk];
        }
        __syncthreads();
        #pragma unroll
        for (int kk = 0; kk < 16; ++kk) {
            int k = kc * 16 + kk;
            float4 s4 = *(const float4*)(sT + k * 36 + n0);
            float4 w4 = *(const float4*)(wc + kk * 132 + j0);
            acc[0][0] = fmaf(s4.x, w4.x, acc[0][0]); acc[0][1] = fmaf(s4.x, w4.y, acc[0][1]);
            acc[0][2] = fmaf(s4.x, w4.z, acc[0][2]); acc[0][3] = fmaf(s4.x, w4.w, acc[0][3]);
            acc[1][0] = fmaf(s4.y, w4.x, acc[1][0]); acc[1][1] = fmaf(s4.y, w4.y, acc[1][1]);
            acc[1][2] = fmaf(s4.y, w4.z, acc[1][2]); acc[1][3] = fmaf(s4.y, w4.w, acc[1][3]);
            acc[2][0] = fmaf(s4.z, w4.x, acc[2][0]); acc[2][1] = fmaf(s4.z, w4.y, acc[2][1]);
            acc[2][2] = fmaf(s4.z, w4.z, acc[2][2]); acc[2][3] = fmaf(s4.z, w4.w, acc[2][3]);
            acc[3][0] = fmaf(s4.w, w4.x, acc[3][0]); acc[3][1] = fmaf(s4.w, w4.y, acc[3][1]);
            acc[3][2] = fmaf(s4.w, w4.z, acc[3][2]); acc[3][3] = fmaf(s4.w, w4.w, acc[3][3]);
        }
    }
    float4 b4 = *(const float4*)(bias + j0);
    #pragma unroll
    for (int i = 0; i < 4; ++i) {
        int gn = nbase + n0 + i;
        if (gn >= N) continue;
        float4 o;
        o.x = acc[i][0] + b4.x;
        o.y = acc[i][1] + b4.y;
        o.z = acc[i][2] + b4.z;
        o.w = acc[i][3] + b4.w;
        *(float4*)(out + (size_t)gn * D + j0) = o;
    }
}

// ==== last-resort fallback: atomic scatter + divide + gemm (proven) ====
__global__ __launch_bounds__(256) void scatter_kernel(
    const float* __restrict__ x, const int* __restrict__ eidx,
    float* summed, float* __restrict__ counts, int E) {
    int t = blockIdx.x * 256 + threadIdx.x;
    int lane = threadIdx.x & 63;
    bool is64 = eidx_is64(eidx);
    int e = t >> 6;
    if (e >= E) return;
    int d = lane * 2;
    int r, c;
    if (is64) { r = eidx[2 * e]; c = eidx[2 * E + 2 * e]; }
    else      { r = eidx[e];     c = eidx[E + e]; }
    float2 v = *(const float2*)(x + (size_t)c * D + d);
    float* dst = summed + (size_t)r * D + d;
    atomicAdd(dst, v.x);
    atomicAdd(dst + 1, v.y);
    if (lane == 0) atomicAdd(counts + r, 1.0f);
}

__global__ __launch_bounds__(256) void divide_kernel(
    float* __restrict__ sums, const float* __restrict__ counts, int N) {
    int g = blockIdx.x * 256 + threadIdx.x;
    int r = g >> 6, lane = g & 63;
    if (r >= N) return;
    float inv = 1.0f / fmaxf(counts[r], 1.0f);
    float2* p = (float2*)(sums + (size_t)r * D + 2 * lane);
    float2 v = *p;
    v.x *= inv; v.y *= inv;
    *p = v;
}

__global__ __launch_bounds__(256) void gemm_kernel(
    float* inout, const float* __restrict__ W,
    const float* __restrict__ bias, int N) {
    __shared__ float sT[128 * 36];
    __shared__ float wc[32 * 132];
    int t = threadIdx.x;
    int nbase = blockIdx.x * 32;
    #pragma unroll
    for (int i = 0; i < 16; ++i) {
        int idx = t + i * 256;
        int n = idx >> 7, k = idx & 127;
        int gn = nbase + n;
        sT[k * 36 + n] = (gn < N) ? inout[(size_t)gn * D + k] : 0.0f;
    }
    int jg = t & 31, ng = t >> 5;
    int j0 = jg * 4, n0 = ng * 4;
    float acc[4][4] = {};
    for (int kc = 0; kc < 4; ++kc) {
        __syncthreads();
        #pragma unroll
        for (int i = 0; i < 16; ++i) {
            int idx = t + i * 256;
            int j = idx >> 5, kk = idx & 31;
            wc[kk * 132 + j] = W[j * D + kc * 32 + kk];
        }
        __syncthreads();
        #pragma unroll 8
        for (int kk = 0; kk < 32; ++kk) {
            int k = kc * 32 + kk;
            float4 s4 = *(const float4*)(sT + k * 36 + n0);
            float4 w4 = *(const float4*)(wc + kk * 132 + j0);
            acc[0][0] = fmaf(s4.x, w4.x, acc[0][0]); acc[0][1] = fmaf(s4.x, w4.y, acc[0][1]);
            acc[0][2] = fmaf(s4.x, w4.z, acc[0][2]); acc[0][3] = fmaf(s4.x, w4.w, acc[0][3]);
            acc[1][0] = fmaf(s4.y, w4.x, acc[1][0]); acc[1][1] = fmaf(s4.y, w4.y, acc[1][1]);
            acc[1][2] = fmaf(s4.y, w4.z, acc[1][2]); acc[1][3] = fmaf(s4.y, w4.w, acc[1][3]);
            acc[2][0] = fmaf(s4.z, w4.x, acc[2][0]); acc[2][1] = fmaf(s4.z, w4.y, acc[2][1]);
            acc[2][2] = fmaf(s4.z, w4.z, acc[2][2]); acc[2][3] = fmaf(s4.z, w4.w, acc[2][3]);
            acc[3][0] = fmaf(s4.w, w4.x, acc[3][0]); acc[3][1] = fmaf(s4.w, w4.y, acc[3][1]);
            acc[3][2] = fmaf(s4.w, w4.z, acc[3][2]); acc[3][3] = fmaf(s4.w, w4.w, acc[3][3]);
        }
    }
    float4 b4 = *(const float4*)(bias + j0);
    #pragma unroll
    for (int i = 0; i < 4; ++i) {
        int gn = nbase + n0 + i;
        if (gn >= N) continue;
        float4 o;
        o.x = acc[i][0] + b4.x;
        o.y = acc[i][1] + b4.y;
        o.z = acc[i][2] + b4.z;
        o.w = acc[i][3] + b4.w;
        *(float4*)(inout + (size_t)gn * D + j0) = o;
    }
}

extern "C" void kernel_launch(void* const* d_in, const int* in_sizes, int n_in,
                              void* d_out, int out_size, void* d_ws, size_t ws_size,
                              hipStream_t stream) {
    // setup_inputs order: x, edge_index, batch_size, num_nodes, W, b
    const float* x = (const float*)d_in[0];
    const int* eidx = (const int*)d_in[1];
    const float* W = (const float*)d_in[4];
    const float* b = (const float*)d_in[5];
    float* out = (float*)d_out;

    int N = in_sizes[0] / D;   // 50000
    int E = in_sizes[1] / 2;   // 800000
    int NBUK = (N + 63) >> BSHIFT;   // 782
    int fb = (N + 31) / 32;
    int ab = (E + EPB_A - 1) / EPB_A;

    // ws layout, 256B-aligned segments.
    size_t o0 = 0;
    size_t o_gc = o0;  o0 += ((size_t)NBUK * 4 + 255) & ~255ULL;
    size_t o_cn = o0;  o0 += ((size_t)N * 4 + 255) & ~255ULL;
    size_t o_st = o0;  o0 += ((size_t)N * 4 + 255) & ~255ULL;
    size_t o_bk = o0;  o0 += (size_t)NBUK * BCAP * 4;
    size_t o_el = o0;  o0 += (size_t)NBUK * BCAP * 4;
    size_t base_need = o0;
    size_t o_xb = o0;  o0 += (((size_t)(N + 1) * D * 2) + 255) & ~255ULL;  // bf16 x + dummy
    size_t o_wb = o0;  size_t bf_need = o0 + (size_t)D * D * 2;            // bf16 W

    bool cap_ok = (N <= 65536) && ((size_t)NBUK * BCAP >= (size_t)E);

    int cvb = (N * D / 8 + 255) / 256;
    int wvb = (D * D / 8 + 255) / 256;   // 8 blocks for W conversion

    if (cap_ok && ws_size >= bf_need) {
        char* ws = (char*)d_ws;
        int*      gcur  = (int*)(ws + o_gc);
        int*      cnt   = (int*)(ws + o_cn);
        int*      start = (int*)(ws + o_st);
        int*      bkt   = (int*)(ws + o_bk);
        int*      elist = (int*)(ws + o_el);
        ushort_t* xb    = (ushort_t*)(ws + o_xb);
        ushort_t* wb    = (ushort_t*)(ws + o_wb);

        hipMemsetAsync(gcur, 0, (size_t)NBUK * 4, stream);  // 3 KB only
        bucketA_kernel<<<ab, 256, 0, stream>>>(eidx, gcur, bkt, E, NBUK);
        prep_kernel<<<NBUK + cvb + wvb, 256, 0, stream>>>(
            gcur, bkt, elist, cnt, start, N, NBUK,
            x, (uint_t*)xb, N * D / 8, cvb, W, (uint_t*)wb);
        fused_bf_kernel<<<fb, 256, 0, stream>>>(xb, elist, cnt, start, wb, b, out, N);
    } else if (cap_ok && ws_size >= base_need) {
        char* ws = (char*)d_ws;
        int* gcur  = (int*)(ws + o_gc);
        int* cnt   = (int*)(ws + o_cn);
        int* start = (int*)(ws + o_st);
        int* bkt   = (int*)(ws + o_bk);
        int* elist = (int*)(ws + o_el);

        hipMemsetAsync(gcur, 0, (size_t)NBUK * 4, stream);
        bucketA_kernel<<<ab, 256, 0, stream>>>(eidx, gcur, bkt, E, NBUK);
        prep_kernel<<<NBUK, 256, 0, stream>>>(
            gcur, bkt, elist, cnt, start, N, NBUK,
            nullptr, nullptr, 0, 0, nullptr, nullptr);
        fused_kernel<<<fb, 256, 0, stream>>>(x, elist, cnt, start, W, b, out, N);
    } else {
        float* counts = (float*)d_ws;
        hipMemsetAsync(d_out, 0, (size_t)N * D * sizeof(float), stream);
        hipMemsetAsync(d_ws, 0, (size_t)N * sizeof(float), stream);
        int sb = (E * 64 + 255) / 256;
        scatter_kernel<<<sb, 256, 0, stream>>>(x, eidx, out, counts, E);
        int db = (N * 64 + 255) / 256;
        divide_kernel<<<db, 256, 0, stream>>>(out, counts, N);
        gemm_kernel<<<fb, 256, 0, stream>>>(out, W, b, N);
    }
}

// Round 4
// 157.389 us; speedup vs baseline: 1.3024x; 1.0452x over previous
//
#include <hip/hip_runtime.h>

#define D 128
#define BSHIFT 6                 // 64 rows per coarse bucket
#define BCAP 1536                // entries per bucket; padded-to-8 mean ~1254, +7.6 sigma
#define EPB_A 2048               // edges per pass-A block: 391 blocks, 8 edges/thread

typedef unsigned short ushort_t;
typedef unsigned int uint_t;
typedef __attribute__((ext_vector_type(8))) short short8_t;   // 8 bf16 = 4 VGPR
typedef __attribute__((ext_vector_type(4))) float f32x4_t;    // mfma C/D

// ---- edge-index dtype probe (int64 vs int32), wave-uniform, ~free ----
__device__ __forceinline__ bool eidx_is64(const int* eidx) {
    int lane = threadIdx.x & 63;
    int probe = eidx[2 * lane + 1];              // L2-hit after first wave
    return __ballot(probe != 0) == 0ULL;         // int64 high halves all zero
}

__device__ __forceinline__ uint_t f2bf(float f) {
    union { float f; uint_t i; } v; v.f = f;
    return (v.i + 0x7fffu + ((v.i >> 16) & 1u)) >> 16;   // RNE
}
__device__ __forceinline__ float bf_lo(uint_t w) {
    union { uint_t i; float f; } v; v.i = w << 16; return v.f;
}
__device__ __forceinline__ float bf_hi(uint_t w) {
    union { uint_t i; float f; } v; v.i = w & 0xffff0000u; return v.f;
}

// ---- Pass A: coarse-bucket edges, single edge read (reg-cached) ----
__global__ __launch_bounds__(256) void bucketA_kernel(
    const int* __restrict__ eidx, int* __restrict__ gcur,
    int* __restrict__ bucket, int E, int NBUK) {
    __shared__ int lhist[1024];   // supports N <= 65536
    __shared__ int lbase[1024];
    bool is64 = eidx_is64(eidx);
    int t = threadIdx.x;
    for (int i = t; i < NBUK; i += 256) lhist[i] = 0;
    __syncthreads();

    int e0 = blockIdx.x * EPB_A;
    int e1 = min(e0 + EPB_A, E);
    int rr[8], cc[8];
    #pragma unroll
    for (int k = 0; k < 8; ++k) {             // read each edge ONCE into regs
        int e = e0 + t + k * 256;
        rr[k] = -1;
        if (e < e1) {
            if (is64) { rr[k] = eidx[2 * e]; cc[k] = eidx[2 * E + 2 * e]; }
            else      { rr[k] = eidx[e];     cc[k] = eidx[E + e]; }
            atomicAdd(&lhist[rr[k] >> BSHIFT], 1);
        }
    }
    __syncthreads();
    for (int i = t; i < NBUK; i += 256) {
        int h = lhist[i];
        lbase[i] = (h > 0) ? atomicAdd(&gcur[i], h) : 0;
        lhist[i] = 0;
    }
    __syncthreads();
    #pragma unroll
    for (int k = 0; k < 8; ++k) {             // scatter from regs (no re-read)
        if (rr[k] >= 0) {
            int b = rr[k] >> BSHIFT;
            int p = atomicAdd(&lhist[b], 1);   // LDS: cheap
            int idx = lbase[b] + p;
            if (idx < BCAP) bucket[b * BCAP + idx] = ((rr[k] & 63) << 24) | cc[k];
        }
    }
}

// ---- Merged Pass B + fp32->bf16 conv of x AND W (independent work) ----
// blocks [0, NBUK): bucket -> packed per-row elist, segments PADDED TO 8
// blocks [NBUK, NBUK+cvb): x fp32 -> bf16 (block NBUK also zeroes dummy row)
// blocks [NBUK+cvb, NBUK+cvb+8): W fp32 -> bf16 (32 KB, for MFMA B-frags)
__global__ __launch_bounds__(256) void prep_kernel(
    const int* __restrict__ gcur, const int* __restrict__ bucket,
    int* __restrict__ elist, int* __restrict__ cnt,
    int* __restrict__ start, int N, int NBUK,
    const float* __restrict__ x, uint_t* __restrict__ xb, int total8, int cvb,
    const float* __restrict__ Wsrc, uint_t* __restrict__ wb) {
    __shared__ int lcnt[64], lpos[64], lstart[64];
    int t = threadIdx.x;

    if ((int)blockIdx.x >= NBUK) {               // ---- conv roles ----
        if (xb == nullptr) return;
        int cb = blockIdx.x - NBUK;
        if (cb < cvb) {                          // x conversion
            int i = cb * 256 + t;
            if (i < total8) {                    // one thread = 8 elems
                const float4* p = (const float4*)(x + (size_t)i * 8);
                float4 a = p[0], b = p[1];
                uint4 o;
                o.x = f2bf(a.x) | (f2bf(a.y) << 16);
                o.y = f2bf(a.z) | (f2bf(a.w) << 16);
                o.z = f2bf(b.x) | (f2bf(b.y) << 16);
                o.w = f2bf(b.z) | (f2bf(b.w) << 16);
                *(uint4*)(xb + (size_t)i * 4) = o;
            }
            if (cb == 0 && t < 16) {
                // dummy zero row at index N (16 * uint4 = 256 B)
                uint4 z; z.x = 0u; z.y = 0u; z.z = 0u; z.w = 0u;
                ((uint4*)(xb + (size_t)N * (D / 2)))[t] = z;
            }
        } else {                                 // W conversion (D*D/8 = 2048 items)
            int i = (cb - cvb) * 256 + t;
            if (i < D * D / 8) {
                const float4* p = (const float4*)(Wsrc + (size_t)i * 8);
                float4 a = p[0], b = p[1];
                uint4 o;
                o.x = f2bf(a.x) | (f2bf(a.y) << 16);
                o.y = f2bf(a.z) | (f2bf(a.w) << 16);
                o.z = f2bf(b.x) | (f2bf(b.y) << 16);
                o.w = f2bf(b.z) | (f2bf(b.w) << 16);
                *(uint4*)(wb + (size_t)i * 4) = o;
            }
        }
        return;
    }

    // ---- bucketB role ----
    int b = blockIdx.x;
    if (t < 64) { lcnt[t] = 0; lpos[t] = 0; }
    __syncthreads();
    int tot = min(gcur[b], BCAP);
    const int* bp = bucket + (size_t)b * BCAP;
    for (int i = t; i < tot; i += 256)
        atomicAdd(&lcnt[bp[i] >> 24], 1);
    __syncthreads();
    if (t == 0) {
        int run = 0;
        #pragma unroll
        for (int i = 0; i < 64; ++i) {
            lstart[i] = run;
            run += (lcnt[i] + 7) & ~7;     // 8-aligned, 8-padded segments
        }
    }
    __syncthreads();
    for (int i = t; i < tot; i += 256) {
        int v = bp[i];
        int rl = v >> 24;
        int p = atomicAdd(&lpos[rl], 1);
        int idx = lstart[rl] + p;
        if (idx < BCAP) elist[(size_t)b * BCAP + idx] = v & 0xFFFFFF;
    }
    // fill padding with the dummy row index (fp32 path reads only i < cnt)
    if (t < 64) {
        int gr = (b << BSHIFT) + t;
        int c0 = lcnt[t];
        int pe = (c0 + 7) & ~7;
        for (int p = c0; p < pe; ++p) {
            int idx = lstart[t] + p;
            if (idx < BCAP) elist[(size_t)b * BCAP + idx] = N;
        }
        if (gr < N) { cnt[gr] = c0; start[gr] = b * BCAP + lstart[t]; }
    }
}

// ---- FUSED mean-aggregate (bf16 gather) + MFMA linear ----
// Phase 1: quarter-wave per row, uint4 (16 B/lane) gathers. DEPTH-16 pipeline:
//   16 outstanding row-gathers per wave (was 8; kernel was latency-bound at
//   8.2 B/cyc/CU with only ~5 KB in flight/CU). elist indices for the next
//   16-chunk are prefetched into regs. Segments 8-padded -> remainder is one
//   8-chunk, no scalar tail; dummies hit the L1-resident zero row at index N.
//   launch_bounds(256,3): VGPR cap 168 (~125 live in the depth-16 body;
//   cap 128 at (256,4) risked spill). 12 waves/CU x 16 outstanding is far
//   past the Little's-law requirement (~5 KB in flight/CU).
// Phase 2: [32x128]x[128x128] on the matrix pipe (mfma_f32_16x16x32_bf16),
//   A from LDS (+8-short row pad), B straight from global bf16 W (L2-hot).
#define GATHER8(CA, CB)                                                       \
    {                                                                         \
        uint4 g0 = *(const uint4*)(xs + (size_t)(CA).x * D);                  \
        uint4 g1 = *(const uint4*)(xs + (size_t)(CA).y * D);                  \
        uint4 g2 = *(const uint4*)(xs + (size_t)(CA).z * D);                  \
        uint4 g3 = *(const uint4*)(xs + (size_t)(CA).w * D);                  \
        uint4 g4 = *(const uint4*)(xs + (size_t)(CB).x * D);                  \
        uint4 g5 = *(const uint4*)(xs + (size_t)(CB).y * D);                  \
        uint4 g6 = *(const uint4*)(xs + (size_t)(CB).z * D);                  \
        uint4 g7 = *(const uint4*)(xs + (size_t)(CB).w * D);                  \
        a0 += ((bf_lo(g0.x) + bf_lo(g1.x)) + (bf_lo(g2.x) + bf_lo(g3.x)))     \
            + ((bf_lo(g4.x) + bf_lo(g5.x)) + (bf_lo(g6.x) + bf_lo(g7.x)));    \
        a1 += ((bf_hi(g0.x) + bf_hi(g1.x)) + (bf_hi(g2.x) + bf_hi(g3.x)))     \
            + ((bf_hi(g4.x) + bf_hi(g5.x)) + (bf_hi(g6.x) + bf_hi(g7.x)));    \
        a2 += ((bf_lo(g0.y) + bf_lo(g1.y)) + (bf_lo(g2.y) + bf_lo(g3.y)))     \
            + ((bf_lo(g4.y) + bf_lo(g5.y)) + (bf_lo(g6.y) + bf_lo(g7.y)));    \
        a3 += ((bf_hi(g0.y) + bf_hi(g1.y)) + (bf_hi(g2.y) + bf_hi(g3.y)))     \
            + ((bf_hi(g4.y) + bf_hi(g5.y)) + (bf_hi(g6.y) + bf_hi(g7.y)));    \
        a4 += ((bf_lo(g0.z) + bf_lo(g1.z)) + (bf_lo(g2.z) + bf_lo(g3.z)))     \
            + ((bf_lo(g4.z) + bf_lo(g5.z)) + (bf_lo(g6.z) + bf_lo(g7.z)));    \
        a5 += ((bf_hi(g0.z) + bf_hi(g1.z)) + (bf_hi(g2.z) + bf_hi(g3.z)))     \
            + ((bf_hi(g4.z) + bf_hi(g5.z)) + (bf_hi(g6.z) + bf_hi(g7.z)));    \
        a6 += ((bf_lo(g0.w) + bf_lo(g1.w)) + (bf_lo(g2.w) + bf_lo(g3.w)))     \
            + ((bf_lo(g4.w) + bf_lo(g5.w)) + (bf_lo(g6.w) + bf_lo(g7.w)));    \
        a7 += ((bf_hi(g0.w) + bf_hi(g1.w)) + (bf_hi(g2.w) + bf_hi(g3.w)))     \
            + ((bf_hi(g4.w) + bf_hi(g5.w)) + (bf_hi(g6.w) + bf_hi(g7.w)));    \
    }

#define GATHER16(CA, CB, CC, CD)                                              \
    {                                                                         \
        uint4 g0 = *(const uint4*)(xs + (size_t)(CA).x * D);                  \
        uint4 g1 = *(const uint4*)(xs + (size_t)(CA).y * D);                  \
        uint4 g2 = *(const uint4*)(xs + (size_t)(CA).z * D);                  \
        uint4 g3 = *(const uint4*)(xs + (size_t)(CA).w * D);                  \
        uint4 g4 = *(const uint4*)(xs + (size_t)(CB).x * D);                  \
        uint4 g5 = *(const uint4*)(xs + (size_t)(CB).y * D);                  \
        uint4 g6 = *(const uint4*)(xs + (size_t)(CB).z * D);                  \
        uint4 g7 = *(const uint4*)(xs + (size_t)(CB).w * D);                  \
        uint4 g8 = *(const uint4*)(xs + (size_t)(CC).x * D);                  \
        uint4 g9 = *(const uint4*)(xs + (size_t)(CC).y * D);                  \
        uint4 ga = *(const uint4*)(xs + (size_t)(CC).z * D);                  \
        uint4 gb = *(const uint4*)(xs + (size_t)(CC).w * D);                  \
        uint4 gc = *(const uint4*)(xs + (size_t)(CD).x * D);                  \
        uint4 gd = *(const uint4*)(xs + (size_t)(CD).y * D);                  \
        uint4 ge = *(const uint4*)(xs + (size_t)(CD).z * D);                  \
        uint4 gf = *(const uint4*)(xs + (size_t)(CD).w * D);                  \
        a0 += (((bf_lo(g0.x) + bf_lo(g1.x)) + (bf_lo(g2.x) + bf_lo(g3.x)))    \
             + ((bf_lo(g4.x) + bf_lo(g5.x)) + (bf_lo(g6.x) + bf_lo(g7.x))))   \
            + (((bf_lo(g8.x) + bf_lo(g9.x)) + (bf_lo(ga.x) + bf_lo(gb.x)))    \
             + ((bf_lo(gc.x) + bf_lo(gd.x)) + (bf_lo(ge.x) + bf_lo(gf.x))));  \
        a1 += (((bf_hi(g0.x) + bf_hi(g1.x)) + (bf_hi(g2.x) + bf_hi(g3.x)))    \
             + ((bf_hi(g4.x) + bf_hi(g5.x)) + (bf_hi(g6.x) + bf_hi(g7.x))))   \
            + (((bf_hi(g8.x) + bf_hi(g9.x)) + (bf_hi(ga.x) + bf_hi(gb.x)))    \
             + ((bf_hi(gc.x) + bf_hi(gd.x)) + (bf_hi(ge.x) + bf_hi(gf.x))));  \
        a2 += (((bf_lo(g0.y) + bf_lo(g1.y)) + (bf_lo(g2.y) + bf_lo(g3.y)))    \
             + ((bf_lo(g4.y) + bf_lo(g5.y)) + (bf_lo(g6.y) + bf_lo(g7.y))))   \
            + (((bf_lo(g8.y) + bf_lo(g9.y)) + (bf_lo(ga.y) + bf_lo(gb.y)))    \
             + ((bf_lo(gc.y) + bf_lo(gd.y)) + (bf_lo(ge.y) + bf_lo(gf.y))));  \
        a3 += (((bf_hi(g0.y) + bf_hi(g1.y)) + (bf_hi(g2.y) + bf_hi(g3.y)))    \
             + ((bf_hi(g4.y) + bf_hi(g5.y)) + (bf_hi(g6.y) + bf_hi(g7.y))))   \
            + (((bf_hi(g8.y) + bf_hi(g9.y)) + (bf_hi(ga.y) + bf_hi(gb.y)))    \
             + ((bf_hi(gc.y) + bf_hi(gd.y)) + (bf_hi(ge.y) + bf_hi(gf.y))));  \
        a4 += (((bf_lo(g0.z) + bf_lo(g1.z)) + (bf_lo(g2.z) + bf_lo(g3.z)))    \
             + ((bf_lo(g4.z) + bf_lo(g5.z)) + (bf_lo(g6.z) + bf_lo(g7.z))))   \
            + (((bf_lo(g8.z) + bf_lo(g9.z)) + (bf_lo(ga.z) + bf_lo(gb.z)))    \
             + ((bf_lo(gc.z) + bf_lo(gd.z)) + (bf_lo(ge.z) + bf_lo(gf.z))));  \
        a5 += (((bf_hi(g0.z) + bf_hi(g1.z)) + (bf_hi(g2.z) + bf_hi(g3.z)))    \
             + ((bf_hi(g4.z) + bf_hi(g5.z)) + (bf_hi(g6.z) + bf_hi(g7.z))))   \
            + (((bf_hi(g8.z) + bf_hi(g9.z)) + (bf_hi(ga.z) + bf_hi(gb.z)))    \
             + ((bf_hi(gc.z) + bf_hi(gd.z)) + (bf_hi(ge.z) + bf_hi(gf.z))));  \
        a6 += (((bf_lo(g0.w) + bf_lo(g1.w)) + (bf_lo(g2.w) + bf_lo(g3.w)))    \
             + ((bf_lo(g4.w) + bf_lo(g5.w)) + (bf_lo(g6.w) + bf_lo(g7.w))))   \
            + (((bf_lo(g8.w) + bf_lo(g9.w)) + (bf_lo(ga.w) + bf_lo(gb.w)))    \
             + ((bf_lo(gc.w) + bf_lo(gd.w)) + (bf_lo(ge.w) + bf_lo(gf.w))));  \
        a7 += (((bf_hi(g0.w) + bf_hi(g1.w)) + (bf_hi(g2.w) + bf_hi(g3.w)))    \
             + ((bf_hi(g4.w) + bf_hi(g5.w)) + (bf_hi(g6.w) + bf_hi(g7.w))))   \
            + (((bf_hi(g8.w) + bf_hi(g9.w)) + (bf_hi(ga.w) + bf_hi(gb.w)))    \
             + ((bf_hi(gc.w) + bf_hi(gd.w)) + (bf_hi(ge.w) + bf_hi(gf.w))));  \
    }

__global__ __launch_bounds__(256, 3) void fused_bf_kernel(
    const ushort_t* __restrict__ xb, const int* __restrict__ elist,
    const int* __restrict__ cnt, const int* __restrict__ start,
    const ushort_t* __restrict__ Wb, const float* __restrict__ bias,
    float* __restrict__ out, int N) {
    __shared__ ushort_t sA[32 * 136];   // 8.5 KiB  [n][k] bf16, +8-short row pad
    int t = threadIdx.x;
    int lane = t & 63, wave = t >> 6;
    int qr = lane >> 4, sl = lane & 15;      // quarter, sublane
    int nbase = blockIdx.x * 32;
    const ushort_t* xs = xb + 8 * sl;        // this lane's 16 B column slice

    // ---- Phase 1: gather means -> bf16 LDS A-tile ----
    #pragma unroll
    for (int quad = 0; quad < 2; ++quad) {
        int n = wave * 8 + quad * 4 + qr;    // this quarter's row
        int gn = nbase + n;
        int nr  = (gn < N) ? cnt[gn]   : 0;  // quarter-uniform
        int beg = (gn < N) ? start[gn] : 0;  // quarter-uniform, 8-aligned
        int nr8 = (nr + 7) & ~7;             // 8-padded trip count
        float a0 = 0.f, a1 = 0.f, a2 = 0.f, a3 = 0.f;
        float a4 = 0.f, a5 = 0.f, a6 = 0.f, a7 = 0.f;
        const int* ep = elist + beg;
        int4 cA = make_int4(0, 0, 0, 0), cB = cA, cC = cA, cD = cA;
        if (16 <= nr8) {
            cA = *(const int4*)(ep);      cB = *(const int4*)(ep + 4);
            cC = *(const int4*)(ep + 8);  cD = *(const int4*)(ep + 12);
        }
        int i = 0;
        while (i + 16 <= nr8) {              // depth-16 pipelined main loop
            int ni = i + 16;
            int4 nA = cA, nB = cB, nC = cC, nD = cD;
            if (ni + 16 <= nr8) {            // prefetch next chunk's elist
                nA = *(const int4*)(ep + ni);      nB = *(const int4*)(ep + ni + 4);
                nC = *(const int4*)(ep + ni + 8);  nD = *(const int4*)(ep + ni + 12);
            }
            GATHER16(cA, cB, cC, cD)
            cA = nA; cB = nB; cC = nC; cD = nD;
            i = ni;
        }
        if (i + 8 <= nr8) {                  // remainder is exactly 0 or 8
            int4 dA = *(const int4*)(ep + i);
            int4 dB = *(const int4*)(ep + i + 4);
            GATHER8(dA, dB)
        }
        float inv = (nr > 0) ? 1.0f / (float)nr : 0.0f;
        uint4 pk;
        pk.x = f2bf(a0 * inv) | (f2bf(a1 * inv) << 16);
        pk.y = f2bf(a2 * inv) | (f2bf(a3 * inv) << 16);
        pk.z = f2bf(a4 * inv) | (f2bf(a5 * inv) << 16);
        pk.w = f2bf(a6 * inv) | (f2bf(a7 * inv) << 16);
        *(uint4*)(sA + n * 136 + 8 * sl) = pk;
    }
    __syncthreads();

    // ---- Phase 2: out[n][j] = mean[n][:] . W[j][:] + b[j]  via MFMA ----
    // wave -> (row-tile rt = wave&1, col-group jgrp = wave>>1 of 4 j-tiles)
    // A-frag: lane holds A[l&15][(l>>4)*8 + e];  B = W^T so lane holds
    // W[j = jt*16 + (l&15)][k .. k+7] -- contiguous global bf16 read.
    {
        int rt = wave & 1, jgrp = wave >> 1;
        int ml = lane & 15, kh = lane >> 4;
        short8_t afr[4];
        #pragma unroll
        for (int ks = 0; ks < 4; ++ks)
            afr[ks] = *(const short8_t*)(sA + (rt * 16 + ml) * 136 + ks * 32 + kh * 8);
        f32x4_t acc[4];
        #pragma unroll
        for (int q = 0; q < 4; ++q) acc[q] = (f32x4_t){0.f, 0.f, 0.f, 0.f};
        #pragma unroll
        for (int q = 0; q < 4; ++q) {
            int j = (jgrp * 4 + q) * 16 + ml;
            #pragma unroll
            for (int ks = 0; ks < 4; ++ks) {
                short8_t bfr = *(const short8_t*)(Wb + (size_t)j * D + ks * 32 + kh * 8);
                acc[q] = __builtin_amdgcn_mfma_f32_16x16x32_bf16(afr[ks], bfr, acc[q], 0, 0, 0);
            }
        }
        // C/D layout: col = lane&15 (j), row = (lane>>4)*4 + reg (n)
        #pragma unroll
        for (int q = 0; q < 4; ++q) {
            int j = (jgrp * 4 + q) * 16 + ml;
            float bj = bias[j];
            #pragma unroll
            for (int r = 0; r < 4; ++r) {
                int gn = nbase + rt * 16 + kh * 4 + r;
                if (gn < N) out[(size_t)gn * D + j] = acc[q][r] + bj;
            }
        }
    }
}

// ---- fp32 fused variant (R10-proven; used when ws can't hold xb).
// Reads only i < cnt entries, so elist padding is invisible to it. ----
__global__ __launch_bounds__(256, 6) void fused_kernel(
    const float* __restrict__ x, const int* __restrict__ elist,
    const int* __restrict__ cnt, const int* __restrict__ start,
    const float* __restrict__ W, const float* __restrict__ bias,
    float* __restrict__ out, int N) {
    __shared__ float sT[128 * 36];
    __shared__ float wc[16 * 132];
    int t = threadIdx.x;
    int lane = t & 63, wave = t >> 6;
    int half = lane >> 5, sl = lane & 31;
    int nbase = blockIdx.x * 32;

    #pragma unroll
    for (int pair = 0; pair < 4; ++pair) {
        int n = wave * 8 + pair * 2 + half;
        int gn = nbase + n;
        int nr  = (gn < N) ? cnt[gn]   : 0;
        int beg = (gn < N) ? start[gn] : 0;
        int nro  = __shfl(nr, lane ^ 32);
        int both = min(nr, nro);
        float ax = 0.f, ay = 0.f, az = 0.f, aw = 0.f;
        int i = 0;
        for (; i + 8 <= both; i += 8) {
            int4 cA = *(const int4*)(elist + beg + i);
            int4 cB = *(const int4*)(elist + beg + i + 4);
            float4 v0 = *(const float4*)(x + (size_t)cA.x * D + 4 * sl);
            float4 v1 = *(const float4*)(x + (size_t)cA.y * D + 4 * sl);
            float4 v2 = *(const float4*)(x + (size_t)cA.z * D + 4 * sl);
            float4 v3 = *(const float4*)(x + (size_t)cA.w * D + 4 * sl);
            float4 v4 = *(const float4*)(x + (size_t)cB.x * D + 4 * sl);
            float4 v5 = *(const float4*)(x + (size_t)cB.y * D + 4 * sl);
            float4 v6 = *(const float4*)(x + (size_t)cB.z * D + 4 * sl);
            float4 v7 = *(const float4*)(x + (size_t)cB.w * D + 4 * sl);
            ax += ((v0.x + v1.x) + (v2.x + v3.x)) + ((v4.x + v5.x) + (v6.x + v7.x));
            ay += ((v0.y + v1.y) + (v2.y + v3.y)) + ((v4.y + v5.y) + (v6.y + v7.y));
            az += ((v0.z + v1.z) + (v2.z + v3.z)) + ((v4.z + v5.z) + (v6.z + v7.z));
            aw += ((v0.w + v1.w) + (v2.w + v3.w)) + ((v4.w + v5.w) + (v6.w + v7.w));
        }
        for (; i < nr; ++i) {
            int c0 = elist[beg + i];
            float4 v = *(const float4*)(x + (size_t)c0 * D + 4 * sl);
            ax += v.x; ay += v.y; az += v.z; aw += v.w;
        }
        float inv = (nr > 0) ? 1.0f / (float)nr : 0.0f;
        int k0 = 4 * sl;
        sT[(k0 + 0) * 36 + n] = ax * inv;
        sT[(k0 + 1) * 36 + n] = ay * inv;
        sT[(k0 + 2) * 36 + n] = az * inv;
        sT[(k0 + 3) * 36 + n] = aw * inv;
    }

    int jg = t & 31, ng = t >> 5;
    int j0 = jg * 4, n0 = ng * 4;
    float acc[4][4] = {};
    for (int kc = 0; kc < 8; ++kc) {
        __syncthreads();
        #pragma unroll
        for (int i = 0; i < 8; ++i) {
            int idx = t + i * 256;
            int j = idx >> 4, kk = idx & 15;
            wc[kk * 132 + j] = W[j * D + kc * 16 + kk];
        }
        __syncthreads();
        #pragma unroll
        for (int kk = 0; kk < 16; ++kk) {
            int k = kc * 16 + kk;
            float4 s4 = *(const float4*)(sT + k * 36 + n0);
            float4 w4 = *(const float4*)(wc + kk * 132 + j0);
            acc[0][0] = fmaf(s4.x, w4.x, acc[0][0]); acc[0][1] = fmaf(s4.x, w4.y, acc[0][1]);
            acc[0][2] = fmaf(s4.x, w4.z, acc[0][2]); acc[0][3] = fmaf(s4.x, w4.w, acc[0][3]);
            acc[1][0] = fmaf(s4.y, w4.x, acc[1][0]); acc[1][1] = fmaf(s4.y, w4.y, acc[1][1]);
            acc[1][2] = fmaf(s4.y, w4.z, acc[1][2]); acc[1][3] = fmaf(s4.y, w4.w, acc[1][3]);
            acc[2][0] = fmaf(s4.z, w4.x, acc[2][0]); acc[2][1] = fmaf(s4.z, w4.y, acc[2][1]);
            acc[2][2] = fmaf(s4.z, w4.z, acc[2][2]); acc[2][3] = fmaf(s4.z, w4.w, acc[2][3]);
            acc[3][0] = fmaf(s4.w, w4.x, acc[3][0]); acc[3][1] = fmaf(s4.w, w4.y, acc[3][1]);
            acc[3][2] = fmaf(s4.w, w4.z, acc[3][2]); acc[3][3] = fmaf(s4.w, w4.w, acc[3][3]);
        }
    }
    float4 b4 = *(const float4*)(bias + j0);
    #pragma unroll
    for (int i = 0; i < 4; ++i) {
        int gn = nbase + n0 + i;
        if (gn >= N) continue;
        float4 o;
        o.x = acc[i][0] + b4.x;
        o.y = acc[i][1] + b4.y;
        o.z = acc[i][2] + b4.z;
        o.w = acc[i][3] + b4.w;
        *(float4*)(out + (size_t)gn * D + j0) = o;
    }
}

// ==== last-resort fallback: atomic scatter + divide + gemm (proven) ====
__global__ __launch_bounds__(256) void scatter_kernel(
    const float* __restrict__ x, const int* __restrict__ eidx,
    float* summed, float* __restrict__ counts, int E) {
    int t = blockIdx.x * 256 + threadIdx.x;
    int lane = threadIdx.x & 63;
    bool is64 = eidx_is64(eidx);
    int e = t >> 6;
    if (e >= E) return;
    int d = lane * 2;
    int r, c;
    if (is64) { r = eidx[2 * e]; c = eidx[2 * E + 2 * e]; }
    else      { r = eidx[e];     c = eidx[E + e]; }
    float2 v = *(const float2*)(x + (size_t)c * D + d);
    float* dst = summed + (size_t)r * D + d;
    atomicAdd(dst, v.x);
    atomicAdd(dst + 1, v.y);
    if (lane == 0) atomicAdd(counts + r, 1.0f);
}

__global__ __launch_bounds__(256) void divide_kernel(
    float* __restrict__ sums, const float* __restrict__ counts, int N) {
    int g = blockIdx.x * 256 + threadIdx.x;
    int r = g >> 6, lane = g & 63;
    if (r >= N) return;
    float inv = 1.0f / fmaxf(counts[r], 1.0f);
    float2* p = (float2*)(sums + (size_t)r * D + 2 * lane);
    float2 v = *p;
    v.x *= inv; v.y *= inv;
    *p = v;
}

__global__ __launch_bounds__(256) void gemm_kernel(
    float* inout, const float* __restrict__ W,
    const float* __restrict__ bias, int N) {
    __shared__ float sT[128 * 36];
    __shared__ float wc[32 * 132];
    int t = threadIdx.x;
    int nbase = blockIdx.x * 32;
    #pragma unroll
    for (int i = 0; i < 16; ++i) {
        int idx = t + i * 256;
        int n = idx >> 7, k = idx & 127;
        int gn = nbase + n;
        sT[k * 36 + n] = (gn < N) ? inout[(size_t)gn * D + k] : 0.0f;
    }
    int jg = t & 31, ng = t >> 5;
    int j0 = jg * 4, n0 = ng * 4;
    float acc[4][4] = {};
    for (int kc = 0; kc < 4; ++kc) {
        __syncthreads();
        #pragma unroll
        for (int i = 0; i < 16; ++i) {
            int idx = t + i * 256;
            int j = idx >> 5, kk = idx & 31;
            wc[kk * 132 + j] = W[j * D + kc * 32 + kk];
        }
        __syncthreads();
        #pragma unroll 8
        for (int kk = 0; kk < 32; ++kk) {
            int k = kc * 32 + kk;
            float4 s4 = *(const float4*)(sT + k * 36 + n0);
            float4 w4 = *(const float4*)(wc + kk * 132 + j0);
            acc[0][0] = fmaf(s4.x, w4.x, acc[0][0]); acc[0][1] = fmaf(s4.x, w4.y, acc[0][1]);
            acc[0][2] = fmaf(s4.x, w4.z, acc[0][2]); acc[0][3] = fmaf(s4.x, w4.w, acc[0][3]);
            acc[1][0] = fmaf(s4.y, w4.x, acc[1][0]); acc[1][1] = fmaf(s4.y, w4.y, acc[1][1]);
            acc[1][2] = fmaf(s4.y, w4.z, acc[1][2]); acc[1][3] = fmaf(s4.y, w4.w, acc[1][3]);
            acc[2][0] = fmaf(s4.z, w4.x, acc[2][0]); acc[2][1] = fmaf(s4.z, w4.y, acc[2][1]);
            acc[2][2] = fmaf(s4.z, w4.z, acc[2][2]); acc[2][3] = fmaf(s4.z, w4.w, acc[2][3]);
            acc[3][0] = fmaf(s4.w, w4.x, acc[3][0]); acc[3][1] = fmaf(s4.w, w4.y, acc[3][1]);
            acc[3][2] = fmaf(s4.w, w4.z, acc[3][2]); acc[3][3] = fmaf(s4.w, w4.w, acc[3][3]);
        }
    }
    float4 b4 = *(const float4*)(bias + j0);
    #pragma unroll
    for (int i = 0; i < 4; ++i) {
        int gn = nbase + n0 + i;
        if (gn >= N) continue;
        float4 o;
        o.x = acc[i][0] + b4.x;
        o.y = acc[i][1] + b4.y;
        o.z = acc[i][2] + b4.z;
        o.w = acc[i][3] + b4.w;
        *(float4*)(inout + (size_t)gn * D + j0) = o;
    }
}

extern "C" void kernel_launch(void* const* d_in, const int* in_sizes, int n_in,
                              void* d_out, int out_size, void* d_ws, size_t ws_size,
                              hipStream_t stream) {
    // setup_inputs order: x, edge_index, batch_size, num_nodes, W, b
    const float* x = (const float*)d_in[0];
    const int* eidx = (const int*)d_in[1];
    const float* W = (const float*)d_in[4];
    const float* b = (const float*)d_in[5];
    float* out = (float*)d_out;

    int N = in_sizes[0] / D;   // 50000
    int E = in_sizes[1] / 2;   // 800000
    int NBUK = (N + 63) >> BSHIFT;   // 782
    int fb = (N + 31) / 32;
    int ab = (E + EPB_A - 1) / EPB_A;

    // ws layout, 256B-aligned segments.
    size_t o0 = 0;
    size_t o_gc = o0;  o0 += ((size_t)NBUK * 4 + 255) & ~255ULL;
    size_t o_cn = o0;  o0 += ((size_t)N * 4 + 255) & ~255ULL;
    size_t o_st = o0;  o0 += ((size_t)N * 4 + 255) & ~255ULL;
    size_t o_bk = o0;  o0 += (size_t)NBUK * BCAP * 4;
    size_t o_el = o0;  o0 += (size_t)NBUK * BCAP * 4;
    size_t base_need = o0;
    size_t o_xb = o0;  o0 += (((size_t)(N + 1) * D * 2) + 255) & ~255ULL;  // bf16 x + dummy
    size_t o_wb = o0;  size_t bf_need = o0 + (size_t)D * D * 2;            // bf16 W

    bool cap_ok = (N <= 65536) && ((size_t)NBUK * BCAP >= (size_t)E);

    int cvb = (N * D / 8 + 255) / 256;
    int wvb = (D * D / 8 + 255) / 256;   // 8 blocks for W conversion

    if (cap_ok && ws_size >= bf_need) {
        char* ws = (char*)d_ws;
        int*      gcur  = (int*)(ws + o_gc);
        int*      cnt   = (int*)(ws + o_cn);
        int*      start = (int*)(ws + o_st);
        int*      bkt   = (int*)(ws + o_bk);
        int*      elist = (int*)(ws + o_el);
        ushort_t* xb    = (ushort_t*)(ws + o_xb);
        ushort_t* wb    = (ushort_t*)(ws + o_wb);

        hipMemsetAsync(gcur, 0, (size_t)NBUK * 4, stream);  // 3 KB only
        bucketA_kernel<<<ab, 256, 0, stream>>>(eidx, gcur, bkt, E, NBUK);
        prep_kernel<<<NBUK + cvb + wvb, 256, 0, stream>>>(
            gcur, bkt, elist, cnt, start, N, NBUK,
            x, (uint_t*)xb, N * D / 8, cvb, W, (uint_t*)wb);
        fused_bf_kernel<<<fb, 256, 0, stream>>>(xb, elist, cnt, start, wb, b, out, N);
    } else if (cap_ok && ws_size >= base_need) {
        char* ws = (char*)d_ws;
        int* gcur  = (int*)(ws + o_gc);
        int* cnt   = (int*)(ws + o_cn);
        int* start = (int*)(ws + o_st);
        int* bkt   = (int*)(ws + o_bk);
        int* elist = (int*)(ws + o_el);

        hipMemsetAsync(gcur, 0, (size_t)NBUK * 4, stream);
        bucketA_kernel<<<ab, 256, 0, stream>>>(eidx, gcur, bkt, E, NBUK);
        prep_kernel<<<NBUK, 256, 0, stream>>>(
            gcur, bkt, elist, cnt, start, N, NBUK,
            nullptr, nullptr, 0, 0, nullptr, nullptr);
        fused_kernel<<<fb, 256, 0, stream>>>(x, elist, cnt, start, W, b, out, N);
    } else {
        float* counts = (float*)d_ws;
        hipMemsetAsync(d_out, 0, (size_t)N * D * sizeof(float), stream);
        hipMemsetAsync(d_ws, 0, (size_t)N * sizeof(float), stream);
        int sb = (E * 64 + 255) / 256;
        scatter_kernel<<<sb, 256, 0, stream>>>(x, eidx, out, counts, E);
        int db = (N * 64 + 255) / 256;
        divide_kernel<<<db, 256, 0, stream>>>(out, counts, N);
        gemm_kernel<<<fb, 256, 0, stream>>>(out, W, b, N);
    }
}

// Round 5
// 156.883 us; speedup vs baseline: 1.3066x; 1.0032x over previous
//
#include <hip/hip_runtime.h>

#define D 128
#define BSHIFT 6                 // 64 rows per coarse bucket
#define BCAP 1536                // raw entries per bucket; mean 1024, +16 sigma
#define EPB_A 2048               // edges per pass-A block

typedef unsigned short ushort_t;
typedef unsigned int uint_t;
typedef __attribute__((ext_vector_type(8))) short short8_t;   // 8 bf16 = 4 VGPR
typedef __attribute__((ext_vector_type(4))) float f32x4_t;    // mfma C/D

// ---- edge-index dtype probe (int64 vs int32), wave-uniform, ~free ----
__device__ __forceinline__ bool eidx_is64(const int* eidx) {
    int lane = threadIdx.x & 63;
    int probe = eidx[2 * lane + 1];              // L2-hit after first wave
    return __ballot(probe != 0) == 0ULL;         // int64 high halves all zero
}

__device__ __forceinline__ uint_t f2bf(float f) {
    union { float f; uint_t i; } v; v.f = f;
    return (v.i + 0x7fffu + ((v.i >> 16) & 1u)) >> 16;   // RNE
}
__device__ __forceinline__ float bf_lo(uint_t w) {
    union { uint_t i; float f; } v; v.i = w << 16; return v.f;
}
__device__ __forceinline__ float bf_hi(uint_t w) {
    union { uint_t i; float f; } v; v.i = w & 0xffff0000u; return v.f;
}

// ==== Kernel 1: bucketA + fp32->bf16 conv of x AND W (all independent) ====
// blocks [0, ab):             coarse-bucket edges (reg-cached single read)
// blocks [ab, ab+cvb):        x fp32 -> bf16 (block ab also zeroes dummy row)
// blocks [ab+cvb, ab+cvb+8):  W fp32 -> bf16
__global__ __launch_bounds__(256) void pre_kernel(
    const int* __restrict__ eidx, int* __restrict__ gcur,
    int* __restrict__ bucket, int E, int NBUK, int ab,
    const float* __restrict__ x, uint_t* __restrict__ xb, int total8, int cvb,
    const float* __restrict__ Wsrc, uint_t* __restrict__ wb, int N) {
    int t = threadIdx.x;

    if ((int)blockIdx.x >= ab) {                 // ---- conv roles ----
        if (xb == nullptr) return;
        int cb = blockIdx.x - ab;
        if (cb < cvb) {                          // x conversion
            int i = cb * 256 + t;
            if (i < total8) {                    // one thread = 8 elems
                const float4* p = (const float4*)(x + (size_t)i * 8);
                float4 a = p[0], b = p[1];
                uint4 o;
                o.x = f2bf(a.x) | (f2bf(a.y) << 16);
                o.y = f2bf(a.z) | (f2bf(a.w) << 16);
                o.z = f2bf(b.x) | (f2bf(b.y) << 16);
                o.w = f2bf(b.z) | (f2bf(b.w) << 16);
                *(uint4*)(xb + (size_t)i * 4) = o;
            }
            if (cb == 0 && t < 16) {
                // dummy zero row at index N (16 * uint4 = 256 B)
                uint4 z; z.x = 0u; z.y = 0u; z.z = 0u; z.w = 0u;
                ((uint4*)(xb + (size_t)N * (D / 2)))[t] = z;
            }
        } else {                                 // W conversion (D*D/8 = 2048 items)
            int i = (cb - cvb) * 256 + t;
            if (i < D * D / 8) {
                const float4* p = (const float4*)(Wsrc + (size_t)i * 8);
                float4 a = p[0], b = p[1];
                uint4 o;
                o.x = f2bf(a.x) | (f2bf(a.y) << 16);
                o.y = f2bf(a.z) | (f2bf(a.w) << 16);
                o.z = f2bf(b.x) | (f2bf(b.y) << 16);
                o.w = f2bf(b.z) | (f2bf(b.w) << 16);
                *(uint4*)(wb + (size_t)i * 4) = o;
            }
        }
        return;
    }

    // ---- bucketA role: coarse-bucket edges, single edge read ----
    __shared__ int lhist[1024];   // supports N <= 65536
    __shared__ int lbase[1024];
    bool is64 = eidx_is64(eidx);
    for (int i = t; i < NBUK; i += 256) lhist[i] = 0;
    __syncthreads();

    int e0 = blockIdx.x * EPB_A;
    int e1 = min(e0 + EPB_A, E);
    int rr[8], cc[8];
    #pragma unroll
    for (int k = 0; k < 8; ++k) {             // read each edge ONCE into regs
        int e = e0 + t + k * 256;
        rr[k] = -1;
        if (e < e1) {
            if (is64) { rr[k] = eidx[2 * e]; cc[k] = eidx[2 * E + 2 * e]; }
            else      { rr[k] = eidx[e];     cc[k] = eidx[E + e]; }
            atomicAdd(&lhist[rr[k] >> BSHIFT], 1);
        }
    }
    __syncthreads();
    for (int i = t; i < NBUK; i += 256) {
        int h = lhist[i];
        lbase[i] = (h > 0) ? atomicAdd(&gcur[i], h) : 0;
        lhist[i] = 0;
    }
    __syncthreads();
    #pragma unroll
    for (int k = 0; k < 8; ++k) {             // scatter from regs (no re-read)
        if (rr[k] >= 0) {
            int b = rr[k] >> BSHIFT;
            int p = atomicAdd(&lhist[b], 1);   // LDS: cheap
            int idx = lbase[b] + p;
            if (idx < BCAP) bucket[b * BCAP + idx] = ((rr[k] & 63) << 24) | cc[k];
        }
    }
}

// ==== Kernel 2: FUSED bucketB (in LDS) + mean-gather (bf16) + MFMA ====
// One 512-thread block per 64-row bucket:
//  step 1: build the packed, 8-padded per-row edge list ENTIRELY IN LDS
//          (count -> serial scan -> scatter -> pad). Kills the elist global
//          round-trip (9 MB), the bucketB kernel, and two launch boundaries.
//  step 2: gather. 32 quarters x 2 rows; quarter = 16 lanes x uint4 = full
//          256 B row, depth-16 in flight; indices via broadcast ds_read_b128.
//          Dummy pad entries hit the L1-resident zero row at index N.
//  step 3: [64x128]x[128x128] on the matrix pipe. 8 waves x 4 MFMA tiles.
#define GATHER8(CA, CB)                                                       \
    {                                                                         \
        uint4 g0 = *(const uint4*)(xs + (size_t)(CA).x * D);                  \
        uint4 g1 = *(const uint4*)(xs + (size_t)(CA).y * D);                  \
        uint4 g2 = *(const uint4*)(xs + (size_t)(CA).z * D);                  \
        uint4 g3 = *(const uint4*)(xs + (size_t)(CA).w * D);                  \
        uint4 g4 = *(const uint4*)(xs + (size_t)(CB).x * D);                  \
        uint4 g5 = *(const uint4*)(xs + (size_t)(CB).y * D);                  \
        uint4 g6 = *(const uint4*)(xs + (size_t)(CB).z * D);                  \
        uint4 g7 = *(const uint4*)(xs + (size_t)(CB).w * D);                  \
        a0 += ((bf_lo(g0.x) + bf_lo(g1.x)) + (bf_lo(g2.x) + bf_lo(g3.x)))     \
            + ((bf_lo(g4.x) + bf_lo(g5.x)) + (bf_lo(g6.x) + bf_lo(g7.x)));    \
        a1 += ((bf_hi(g0.x) + bf_hi(g1.x)) + (bf_hi(g2.x) + bf_hi(g3.x)))     \
            + ((bf_hi(g4.x) + bf_hi(g5.x)) + (bf_hi(g6.x) + bf_hi(g7.x)));    \
        a2 += ((bf_lo(g0.y) + bf_lo(g1.y)) + (bf_lo(g2.y) + bf_lo(g3.y)))     \
            + ((bf_lo(g4.y) + bf_lo(g5.y)) + (bf_lo(g6.y) + bf_lo(g7.y)));    \
        a3 += ((bf_hi(g0.y) + bf_hi(g1.y)) + (bf_hi(g2.y) + bf_hi(g3.y)))     \
            + ((bf_hi(g4.y) + bf_hi(g5.y)) + (bf_hi(g6.y) + bf_hi(g7.y)));    \
        a4 += ((bf_lo(g0.z) + bf_lo(g1.z)) + (bf_lo(g2.z) + bf_lo(g3.z)))     \
            + ((bf_lo(g4.z) + bf_lo(g5.z)) + (bf_lo(g6.z) + bf_lo(g7.z)));    \
        a5 += ((bf_hi(g0.z) + bf_hi(g1.z)) + (bf_hi(g2.z) + bf_hi(g3.z)))     \
            + ((bf_hi(g4.z) + bf_hi(g5.z)) + (bf_hi(g6.z) + bf_hi(g7.z)));    \
        a6 += ((bf_lo(g0.w) + bf_lo(g1.w)) + (bf_lo(g2.w) + bf_lo(g3.w)))     \
            + ((bf_lo(g4.w) + bf_lo(g5.w)) + (bf_lo(g6.w) + bf_lo(g7.w)));    \
        a7 += ((bf_hi(g0.w) + bf_hi(g1.w)) + (bf_hi(g2.w) + bf_hi(g3.w)))     \
            + ((bf_hi(g4.w) + bf_hi(g5.w)) + (bf_hi(g6.w) + bf_hi(g7.w)));    \
    }

#define GATHER16(CA, CB, CC, CD)                                              \
    {                                                                         \
        uint4 g0 = *(const uint4*)(xs + (size_t)(CA).x * D);                  \
        uint4 g1 = *(const uint4*)(xs + (size_t)(CA).y * D);                  \
        uint4 g2 = *(const uint4*)(xs + (size_t)(CA).z * D);                  \
        uint4 g3 = *(const uint4*)(xs + (size_t)(CA).w * D);                  \
        uint4 g4 = *(const uint4*)(xs + (size_t)(CB).x * D);                  \
        uint4 g5 = *(const uint4*)(xs + (size_t)(CB).y * D);                  \
        uint4 g6 = *(const uint4*)(xs + (size_t)(CB).z * D);                  \
        uint4 g7 = *(const uint4*)(xs + (size_t)(CB).w * D);                  \
        uint4 g8 = *(const uint4*)(xs + (size_t)(CC).x * D);                  \
        uint4 g9 = *(const uint4*)(xs + (size_t)(CC).y * D);                  \
        uint4 ga = *(const uint4*)(xs + (size_t)(CC).z * D);                  \
        uint4 gb = *(const uint4*)(xs + (size_t)(CC).w * D);                  \
        uint4 gc = *(const uint4*)(xs + (size_t)(CD).x * D);                  \
        uint4 gd = *(const uint4*)(xs + (size_t)(CD).y * D);                  \
        uint4 ge = *(const uint4*)(xs + (size_t)(CD).z * D);                  \
        uint4 gf = *(const uint4*)(xs + (size_t)(CD).w * D);                  \
        a0 += (((bf_lo(g0.x) + bf_lo(g1.x)) + (bf_lo(g2.x) + bf_lo(g3.x)))    \
             + ((bf_lo(g4.x) + bf_lo(g5.x)) + (bf_lo(g6.x) + bf_lo(g7.x))))   \
            + (((bf_lo(g8.x) + bf_lo(g9.x)) + (bf_lo(ga.x) + bf_lo(gb.x)))    \
             + ((bf_lo(gc.x) + bf_lo(gd.x)) + (bf_lo(ge.x) + bf_lo(gf.x))));  \
        a1 += (((bf_hi(g0.x) + bf_hi(g1.x)) + (bf_hi(g2.x) + bf_hi(g3.x)))    \
             + ((bf_hi(g4.x) + bf_hi(g5.x)) + (bf_hi(g6.x) + bf_hi(g7.x))))   \
            + (((bf_hi(g8.x) + bf_hi(g9.x)) + (bf_hi(ga.x) + bf_hi(gb.x)))    \
             + ((bf_hi(gc.x) + bf_hi(gd.x)) + (bf_hi(ge.x) + bf_hi(gf.x))));  \
        a2 += (((bf_lo(g0.y) + bf_lo(g1.y)) + (bf_lo(g2.y) + bf_lo(g3.y)))    \
             + ((bf_lo(g4.y) + bf_lo(g5.y)) + (bf_lo(g6.y) + bf_lo(g7.y))))   \
            + (((bf_lo(g8.y) + bf_lo(g9.y)) + (bf_lo(ga.y) + bf_lo(gb.y)))    \
             + ((bf_lo(gc.y) + bf_lo(gd.y)) + (bf_lo(ge.y) + bf_lo(gf.y))));  \
        a3 += (((bf_hi(g0.y) + bf_hi(g1.y)) + (bf_hi(g2.y) + bf_hi(g3.y)))    \
             + ((bf_hi(g4.y) + bf_hi(g5.y)) + (bf_hi(g6.y) + bf_hi(g7.y))))   \
            + (((bf_hi(g8.y) + bf_hi(g9.y)) + (bf_hi(ga.y) + bf_hi(gb.y)))    \
             + ((bf_hi(gc.y) + bf_hi(gd.y)) + (bf_hi(ge.y) + bf_hi(gf.y))));  \
        a4 += (((bf_lo(g0.z) + bf_lo(g1.z)) + (bf_lo(g2.z) + bf_lo(g3.z)))    \
             + ((bf_lo(g4.z) + bf_lo(g5.z)) + (bf_lo(g6.z) + bf_lo(g7.z))))   \
            + (((bf_lo(g8.z) + bf_lo(g9.z)) + (bf_lo(ga.z) + bf_lo(gb.z)))    \
             + ((bf_lo(gc.z) + bf_lo(gd.z)) + (bf_lo(ge.z) + bf_lo(gf.z))));  \
        a5 += (((bf_hi(g0.z) + bf_hi(g1.z)) + (bf_hi(g2.z) + bf_hi(g3.z)))    \
             + ((bf_hi(g4.z) + bf_hi(g5.z)) + (bf_hi(g6.z) + bf_hi(g7.z))))   \
            + (((bf_hi(g8.z) + bf_hi(g9.z)) + (bf_hi(ga.z) + bf_hi(gb.z)))    \
             + ((bf_hi(gc.z) + bf_hi(gd.z)) + (bf_hi(ge.z) + bf_hi(gf.z))));  \
        a6 += (((bf_lo(g0.w) + bf_lo(g1.w)) + (bf_lo(g2.w) + bf_lo(g3.w)))    \
             + ((bf_lo(g4.w) + bf_lo(g5.w)) + (bf_lo(g6.w) + bf_lo(g7.w))))   \
            + (((bf_lo(g8.w) + bf_lo(g9.w)) + (bf_lo(ga.w) + bf_lo(gb.w)))    \
             + ((bf_lo(gc.w) + bf_lo(gd.w)) + (bf_lo(ge.w) + bf_lo(gf.w))));  \
        a7 += (((bf_hi(g0.w) + bf_hi(g1.w)) + (bf_hi(g2.w) + bf_hi(g3.w)))    \
             + ((bf_hi(g4.w) + bf_hi(g5.w)) + (bf_hi(g6.w) + bf_hi(g7.w))))   \
            + (((bf_hi(g8.w) + bf_hi(g9.w)) + (bf_hi(ga.w) + bf_hi(gb.w)))    \
             + ((bf_hi(gc.w) + bf_hi(gd.w)) + (bf_hi(ge.w) + bf_hi(gf.w))));  \
    }

__global__ __launch_bounds__(512, 2) void fused_bf_kernel(
    const ushort_t* __restrict__ xb, const int* __restrict__ gcur,
    const int* __restrict__ bucket, const ushort_t* __restrict__ Wb,
    const float* __restrict__ bias, float* __restrict__ out, int N) {
    __shared__ int sE[2048];            // 8 KiB   packed 8-padded edge list
    __shared__ int lcnt[64], lpos[64], lstart[64];
    __shared__ ushort_t sA[64 * 136];   // 17 KiB  [n][k] bf16, +8-short row pad
    int t = threadIdx.x;
    int b = blockIdx.x;

    // ---- step 1: bucketB in LDS ----
    if (t < 64) { lcnt[t] = 0; lpos[t] = 0; }
    __syncthreads();
    int tot = min(gcur[b], BCAP);
    const int* bp = bucket + (size_t)b * BCAP;
    for (int i = t; i < tot; i += 512)
        atomicAdd(&lcnt[bp[i] >> 24], 1);
    __syncthreads();
    if (t == 0) {
        int run = 0;
        #pragma unroll
        for (int i = 0; i < 64; ++i) {
            lstart[i] = run;
            run += (lcnt[i] + 7) & ~7;     // 8-aligned, 8-padded segments
        }                                  // run <= 1536 + 64*7 = 1984 < 2048
    }
    __syncthreads();
    for (int i = t; i < tot; i += 512) {
        int v = bp[i];
        int rl = v >> 24;
        int p = atomicAdd(&lpos[rl], 1);
        int idx = lstart[rl] + p;
        if (idx < 2048) sE[idx] = v & 0xFFFFFF;
    }
    if (t < 64) {                          // pad with dummy (zero) row index N
        int c0 = lcnt[t];
        int pe = (c0 + 7) & ~7;
        for (int p = c0; p < pe; ++p) {
            int idx = lstart[t] + p;
            if (idx < 2048) sE[idx] = N;
        }
    }
    __syncthreads();

    // ---- step 2: gather means -> bf16 LDS A-tile ----
    int lane = t & 63, wave = t >> 6;
    int qi = t >> 4, sl = t & 15;          // quarter [0,32), sublane [0,16)
    int nbase = b << BSHIFT;               // 64 rows per block
    const ushort_t* xs = xb + 8 * sl;      // this lane's 16 B column slice

    #pragma unroll
    for (int quad = 0; quad < 2; ++quad) {
        int n = 2 * qi + quad;             // row within bucket [0,64)
        int nr  = lcnt[n];                 // rows >= N have no entries -> 0
        int st  = lstart[n];               // 8-aligned (32 B for int4 reads)
        int nr8 = (nr + 7) & ~7;
        float a0 = 0.f, a1 = 0.f, a2 = 0.f, a3 = 0.f;
        float a4 = 0.f, a5 = 0.f, a6 = 0.f, a7 = 0.f;
        int i = 0;
        for (; i + 16 <= nr8; i += 16) {   // depth-16 main loop, LDS indices
            int4 cA = *(const int4*)(sE + st + i);
            int4 cB = *(const int4*)(sE + st + i + 4);
            int4 cC = *(const int4*)(sE + st + i + 8);
            int4 cD = *(const int4*)(sE + st + i + 12);
            GATHER16(cA, cB, cC, cD)
        }
        if (i + 8 <= nr8) {                // remainder is exactly 0 or 8
            int4 dA = *(const int4*)(sE + st + i);
            int4 dB = *(const int4*)(sE + st + i + 4);
            GATHER8(dA, dB)
        }
        float inv = (nr > 0) ? 1.0f / (float)nr : 0.0f;
        uint4 pk;
        pk.x = f2bf(a0 * inv) | (f2bf(a1 * inv) << 16);
        pk.y = f2bf(a2 * inv) | (f2bf(a3 * inv) << 16);
        pk.z = f2bf(a4 * inv) | (f2bf(a5 * inv) << 16);
        pk.w = f2bf(a6 * inv) | (f2bf(a7 * inv) << 16);
        *(uint4*)(sA + n * 136 + 8 * sl) = pk;
    }
    __syncthreads();

    // ---- step 3: out[n][j] = mean[n][:] . W[j][:] + b[j]  via MFMA ----
    // 8 waves: rt = wave&3 (4 row-tiles of 16), jgrp = wave>>2 (2 groups of
    // 4 j-tiles). A-frag from LDS; B = W^T straight from global bf16 W.
    {
        int rt = wave & 3, jgrp = wave >> 2;
        int ml = lane & 15, kh = lane >> 4;
        short8_t afr[4];
        #pragma unroll
        for (int ks = 0; ks < 4; ++ks)
            afr[ks] = *(const short8_t*)(sA + (rt * 16 + ml) * 136 + ks * 32 + kh * 8);
        f32x4_t acc[4];
        #pragma unroll
        for (int q = 0; q < 4; ++q) acc[q] = (f32x4_t){0.f, 0.f, 0.f, 0.f};
        #pragma unroll
        for (int q = 0; q < 4; ++q) {
            int j = (jgrp * 4 + q) * 16 + ml;
            #pragma unroll
            for (int ks = 0; ks < 4; ++ks) {
                short8_t bfr = *(const short8_t*)(Wb + (size_t)j * D + ks * 32 + kh * 8);
                acc[q] = __builtin_amdgcn_mfma_f32_16x16x32_bf16(afr[ks], bfr, acc[q], 0, 0, 0);
            }
        }
        // C/D layout: col = lane&15 (j), row = (lane>>4)*4 + reg (n)
        #pragma unroll
        for (int q = 0; q < 4; ++q) {
            int j = (jgrp * 4 + q) * 16 + ml;
            float bj = bias[j];
            #pragma unroll
            for (int r = 0; r < 4; ++r) {
                int gn = nbase + rt * 16 + kh * 4 + r;
                if (gn < N) out[(size_t)gn * D + j] = acc[q][r] + bj;
            }
        }
    }
}

// ---- fallback Pass B: bucket -> packed global elist (fp32 path only) ----
__global__ __launch_bounds__(256) void prep_kernel(
    const int* __restrict__ gcur, const int* __restrict__ bucket,
    int* __restrict__ elist, int* __restrict__ cnt,
    int* __restrict__ start, int N, int NBUK) {
    __shared__ int lcnt[64], lpos[64], lstart[64];
    int t = threadIdx.x;
    int b = blockIdx.x;
    if (t < 64) { lcnt[t] = 0; lpos[t] = 0; }
    __syncthreads();
    int tot = min(gcur[b], BCAP);
    const int* bp = bucket + (size_t)b * BCAP;
    for (int i = t; i < tot; i += 256)
        atomicAdd(&lcnt[bp[i] >> 24], 1);
    __syncthreads();
    if (t == 0) {
        int run = 0;
        #pragma unroll
        for (int i = 0; i < 64; ++i) {
            lstart[i] = run;
            run += (lcnt[i] + 3) & ~3;     // 4-aligned segments
        }
    }
    __syncthreads();
    for (int i = t; i < tot; i += 256) {
        int v = bp[i];
        int rl = v >> 24;
        int p = atomicAdd(&lpos[rl], 1);
        int idx = lstart[rl] + p;
        if (idx < BCAP) elist[(size_t)b * BCAP + idx] = v & 0xFFFFFF;
    }
    if (t < 64) {
        int gr = (b << BSHIFT) + t;
        if (gr < N) { cnt[gr] = lcnt[t]; start[gr] = b * BCAP + lstart[t]; }
    }
}

// ---- fp32 fused variant (proven; used when ws can't hold xb).
// Reads only i < cnt entries. ----
__global__ __launch_bounds__(256, 6) void fused_kernel(
    const float* __restrict__ x, const int* __restrict__ elist,
    const int* __restrict__ cnt, const int* __restrict__ start,
    const float* __restrict__ W, const float* __restrict__ bias,
    float* __restrict__ out, int N) {
    __shared__ float sT[128 * 36];
    __shared__ float wc[16 * 132];
    int t = threadIdx.x;
    int lane = t & 63, wave = t >> 6;
    int half = lane >> 5, sl = lane & 31;
    int nbase = blockIdx.x * 32;

    #pragma unroll
    for (int pair = 0; pair < 4; ++pair) {
        int n = wave * 8 + pair * 2 + half;
        int gn = nbase + n;
        int nr  = (gn < N) ? cnt[gn]   : 0;
        int beg = (gn < N) ? start[gn] : 0;
        int nro  = __shfl(nr, lane ^ 32);
        int both = min(nr, nro);
        float ax = 0.f, ay = 0.f, az = 0.f, aw = 0.f;
        int i = 0;
        for (; i + 8 <= both; i += 8) {
            int4 cA = *(const int4*)(elist + beg + i);
            int4 cB = *(const int4*)(elist + beg + i + 4);
            float4 v0 = *(const float4*)(x + (size_t)cA.x * D + 4 * sl);
            float4 v1 = *(const float4*)(x + (size_t)cA.y * D + 4 * sl);
            float4 v2 = *(const float4*)(x + (size_t)cA.z * D + 4 * sl);
            float4 v3 = *(const float4*)(x + (size_t)cA.w * D + 4 * sl);
            float4 v4 = *(const float4*)(x + (size_t)cB.x * D + 4 * sl);
            float4 v5 = *(const float4*)(x + (size_t)cB.y * D + 4 * sl);
            float4 v6 = *(const float4*)(x + (size_t)cB.z * D + 4 * sl);
            float4 v7 = *(const float4*)(x + (size_t)cB.w * D + 4 * sl);
            ax += ((v0.x + v1.x) + (v2.x + v3.x)) + ((v4.x + v5.x) + (v6.x + v7.x));
            ay += ((v0.y + v1.y) + (v2.y + v3.y)) + ((v4.y + v5.y) + (v6.y + v7.y));
            az += ((v0.z + v1.z) + (v2.z + v3.z)) + ((v4.z + v5.z) + (v6.z + v7.z));
            aw += ((v0.w + v1.w) + (v2.w + v3.w)) + ((v4.w + v5.w) + (v6.w + v7.w));
        }
        for (; i < nr; ++i) {
            int c0 = elist[beg + i];
            float4 v = *(const float4*)(x + (size_t)c0 * D + 4 * sl);
            ax += v.x; ay += v.y; az += v.z; aw += v.w;
        }
        float inv = (nr > 0) ? 1.0f / (float)nr : 0.0f;
        int k0 = 4 * sl;
        sT[(k0 + 0) * 36 + n] = ax * inv;
        sT[(k0 + 1) * 36 + n] = ay * inv;
        sT[(k0 + 2) * 36 + n] = az * inv;
        sT[(k0 + 3) * 36 + n] = aw * inv;
    }

    int jg = t & 31, ng = t >> 5;
    int j0 = jg * 4, n0 = ng * 4;
    float acc[4][4] = {};
    for (int kc = 0; kc < 8; ++kc) {
        __syncthreads();
        #pragma unroll
        for (int i = 0; i < 8; ++i) {
            int idx = t + i * 256;
            int j = idx >> 4, kk = idx & 15;
            wc[kk * 132 + j] = W[j * D + kc * 16 + kk];
        }
        __syncthreads();
        #pragma unroll
        for (int kk = 0; kk < 16; ++kk) {
            int k = kc * 16 + kk;
            float4 s4 = *(const float4*)(sT + k * 36 + n0);
            float4 w4 = *(const float4*)(wc + kk * 132 + j0);
            acc[0][0] = fmaf(s4.x, w4.x, acc[0][0]); acc[0][1] = fmaf(s4.x, w4.y, acc[0][1]);
            acc[0][2] = fmaf(s4.x, w4.z, acc[0][2]); acc[0][3] = fmaf(s4.x, w4.w, acc[0][3]);
            acc[1][0] = fmaf(s4.y, w4.x, acc[1][0]); acc[1][1] = fmaf(s4.y, w4.y, acc[1][1]);
            acc[1][2] = fmaf(s4.y, w4.z, acc[1][2]); acc[1][3] = fmaf(s4.y, w4.w, acc[1][3]);
            acc[2][0] = fmaf(s4.z, w4.x, acc[2][0]); acc[2][1] = fmaf(s4.z, w4.y, acc[2][1]);
            acc[2][2] = fmaf(s4.z, w4.z, acc[2][2]); acc[2][3] = fmaf(s4.z, w4.w, acc[2][3]);
            acc[3][0] = fmaf(s4.w, w4.x, acc[3][0]); acc[3][1] = fmaf(s4.w, w4.y, acc[3][1]);
            acc[3][2] = fmaf(s4.w, w4.z, acc[3][2]); acc[3][3] = fmaf(s4.w, w4.w, acc[3][3]);
        }
    }
    float4 b4 = *(const float4*)(bias + j0);
    #pragma unroll
    for (int i = 0; i < 4; ++i) {
        int gn = nbase + n0 + i;
        if (gn >= N) continue;
        float4 o;
        o.x = acc[i][0] + b4.x;
        o.y = acc[i][1] + b4.y;
        o.z = acc[i][2] + b4.z;
        o.w = acc[i][3] + b4.w;
        *(float4*)(out + (size_t)gn * D + j0) = o;
    }
}

// ==== last-resort fallback: atomic scatter + divide + gemm (proven) ====
__global__ __launch_bounds__(256) void scatter_kernel(
    const float* __restrict__ x, const int* __restrict__ eidx,
    float* summed, float* __restrict__ counts, int E) {
    int t = blockIdx.x * 256 + threadIdx.x;
    int lane = threadIdx.x & 63;
    bool is64 = eidx_is64(eidx);
    int e = t >> 6;
    if (e >= E) return;
    int d = lane * 2;
    int r, c;
    if (is64) { r = eidx[2 * e]; c = eidx[2 * E + 2 * e]; }
    else      { r = eidx[e];     c = eidx[E + e]; }
    float2 v = *(const float2*)(x + (size_t)c * D + d);
    float* dst = summed + (size_t)r * D + d;
    atomicAdd(dst, v.x);
    atomicAdd(dst + 1, v.y);
    if (lane == 0) atomicAdd(counts + r, 1.0f);
}

__global__ __launch_bounds__(256) void divide_kernel(
    float* __restrict__ sums, const float* __restrict__ counts, int N) {
    int g = blockIdx.x * 256 + threadIdx.x;
    int r = g >> 6, lane = g & 63;
    if (r >= N) return;
    float inv = 1.0f / fmaxf(counts[r], 1.0f);
    float2* p = (float2*)(sums + (size_t)r * D + 2 * lane);
    float2 v = *p;
    v.x *= inv; v.y *= inv;
    *p = v;
}

__global__ __launch_bounds__(256) void gemm_kernel(
    float* inout, const float* __restrict__ W,
    const float* __restrict__ bias, int N) {
    __shared__ float sT[128 * 36];
    __shared__ float wc[32 * 132];
    int t = threadIdx.x;
    int nbase = blockIdx.x * 32;
    #pragma unroll
    for (int i = 0; i < 16; ++i) {
        int idx = t + i * 256;
        int n = idx >> 7, k = idx & 127;
        int gn = nbase + n;
        sT[k * 36 + n] = (gn < N) ? inout[(size_t)gn * D + k] : 0.0f;
    }
    int jg = t & 31, ng = t >> 5;
    int j0 = jg * 4, n0 = ng * 4;
    float acc[4][4] = {};
    for (int kc = 0; kc < 4; ++kc) {
        __syncthreads();
        #pragma unroll
        for (int i = 0; i < 16; ++i) {
            int idx = t + i * 256;
            int j = idx >> 5, kk = idx & 31;
            wc[kk * 132 + j] = W[j * D + kc * 32 + kk];
        }
        __syncthreads();
        #pragma unroll 8
        for (int kk = 0; kk < 32; ++kk) {
            int k = kc * 32 + kk;
            float4 s4 = *(const float4*)(sT + k * 36 + n0);
            float4 w4 = *(const float4*)(wc + kk * 132 + j0);
            acc[0][0] = fmaf(s4.x, w4.x, acc[0][0]); acc[0][1] = fmaf(s4.x, w4.y, acc[0][1]);
            acc[0][2] = fmaf(s4.x, w4.z, acc[0][2]); acc[0][3] = fmaf(s4.x, w4.w, acc[0][3]);
            acc[1][0] = fmaf(s4.y, w4.x, acc[1][0]); acc[1][1] = fmaf(s4.y, w4.y, acc[1][1]);
            acc[1][2] = fmaf(s4.y, w4.z, acc[1][2]); acc[1][3] = fmaf(s4.y, w4.w, acc[1][3]);
            acc[2][0] = fmaf(s4.z, w4.x, acc[2][0]); acc[2][1] = fmaf(s4.z, w4.y, acc[2][1]);
            acc[2][2] = fmaf(s4.z, w4.z, acc[2][2]); acc[2][3] = fmaf(s4.z, w4.w, acc[2][3]);
            acc[3][0] = fmaf(s4.w, w4.x, acc[3][0]); acc[3][1] = fmaf(s4.w, w4.y, acc[3][1]);
            acc[3][2] = fmaf(s4.w, w4.z, acc[3][2]); acc[3][3] = fmaf(s4.w, w4.w, acc[3][3]);
        }
    }
    float4 b4 = *(const float4*)(bias + j0);
    #pragma unroll
    for (int i = 0; i < 4; ++i) {
        int gn = nbase + n0 + i;
        if (gn >= N) continue;
        float4 o;
        o.x = acc[i][0] + b4.x;
        o.y = acc[i][1] + b4.y;
        o.z = acc[i][2] + b4.z;
        o.w = acc[i][3] + b4.w;
        *(float4*)(inout + (size_t)gn * D + j0) = o;
    }
}

extern "C" void kernel_launch(void* const* d_in, const int* in_sizes, int n_in,
                              void* d_out, int out_size, void* d_ws, size_t ws_size,
                              hipStream_t stream) {
    // setup_inputs order: x, edge_index, batch_size, num_nodes, W, b
    const float* x = (const float*)d_in[0];
    const int* eidx = (const int*)d_in[1];
    const float* W = (const float*)d_in[4];
    const float* b = (const float*)d_in[5];
    float* out = (float*)d_out;

    int N = in_sizes[0] / D;   // 50000
    int E = in_sizes[1] / 2;   // 800000
    int NBUK = (N + 63) >> BSHIFT;   // 782
    int ab = (E + EPB_A - 1) / EPB_A;

    // ws layout, 256B-aligned segments (cnt/start/elist used by fallback only).
    size_t o0 = 0;
    size_t o_gc = o0;  o0 += ((size_t)NBUK * 4 + 255) & ~255ULL;
    size_t o_cn = o0;  o0 += ((size_t)N * 4 + 255) & ~255ULL;
    size_t o_st = o0;  o0 += ((size_t)N * 4 + 255) & ~255ULL;
    size_t o_bk = o0;  o0 += (size_t)NBUK * BCAP * 4;
    size_t o_el = o0;  o0 += (size_t)NBUK * BCAP * 4;
    size_t base_need = o0;
    size_t o_xb = o0;  o0 += (((size_t)(N + 1) * D * 2) + 255) & ~255ULL;  // bf16 x + dummy
    size_t o_wb = o0;  size_t bf_need = o0 + (size_t)D * D * 2;            // bf16 W

    bool cap_ok = (N <= 65536) && ((size_t)NBUK * BCAP >= (size_t)E);

    int cvb = (N * D / 8 + 255) / 256;
    int wvb = (D * D / 8 + 255) / 256;   // 8 blocks for W conversion

    if (cap_ok && ws_size >= bf_need) {
        char* ws = (char*)d_ws;
        int*      gcur  = (int*)(ws + o_gc);
        int*      bkt   = (int*)(ws + o_bk);
        ushort_t* xb    = (ushort_t*)(ws + o_xb);
        ushort_t* wb    = (ushort_t*)(ws + o_wb);

        hipMemsetAsync(gcur, 0, (size_t)NBUK * 4, stream);  // 3 KB only
        pre_kernel<<<ab + cvb + wvb, 256, 0, stream>>>(
            eidx, gcur, bkt, E, NBUK, ab,
            x, (uint_t*)xb, N * D / 8, cvb, W, (uint_t*)wb, N);
        fused_bf_kernel<<<NBUK, 512, 0, stream>>>(xb, gcur, bkt, wb, b, out, N);
    } else if (cap_ok && ws_size >= base_need) {
        char* ws = (char*)d_ws;
        int* gcur  = (int*)(ws + o_gc);
        int* cnt   = (int*)(ws + o_cn);
        int* start = (int*)(ws + o_st);
        int* bkt   = (int*)(ws + o_bk);
        int* elist = (int*)(ws + o_el);
        int fb = (N + 31) / 32;

        hipMemsetAsync(gcur, 0, (size_t)NBUK * 4, stream);
        pre_kernel<<<ab, 256, 0, stream>>>(
            eidx, gcur, bkt, E, NBUK, ab,
            nullptr, nullptr, 0, 0, nullptr, nullptr, N);
        prep_kernel<<<NBUK, 256, 0, stream>>>(gcur, bkt, elist, cnt, start, N, NBUK);
        fused_kernel<<<fb, 256, 0, stream>>>(x, elist, cnt, start, W, b, out, N);
    } else {
        float* counts = (float*)d_ws;
        int fb = (N + 31) / 32;
        hipMemsetAsync(d_out, 0, (size_t)N * D * sizeof(float), stream);
        hipMemsetAsync(d_ws, 0, (size_t)N * sizeof(float), stream);
        int sb = (E * 64 + 255) / 256;
        scatter_kernel<<<sb, 256, 0, stream>>>(x, eidx, out, counts, E);
        int db = (N * 64 + 255) / 256;
        divide_kernel<<<db, 256, 0, stream>>>(out, counts, N);
        gemm_kernel<<<fb, 256, 0, stream>>>(out, W, b, N);
    }
}